// Round 3
// baseline (14714.053 us; speedup 1.0000x reference)
//
#include <hip/hip_runtime.h>
#include <math.h>

#define NS 100000
#define NB 50000
#define EE 1600000

#define BSHIFT 6
#define BSIZE 64                       // dst nodes per bucket
#define NBKT_S ((NS + BSIZE - 1) / BSIZE)   // 1563
#define NBKT_B ((NB + BSIZE - 1) / BSIZE)   // 782
#define BOFF_STRIDE (NBKT_S + 1)       // 1564
#define CHUNK 16384
#define NBLKS ((EE + CHUNK - 1) / CHUNK)    // 98
#define EPAD (NBLKS * CHUNK)

#define SRC_MASK 0x1FFFF
#define SLOT_SHIFT 17
#define MAXINIT 0x007FFFFFu            // mapf(-inf)

__device__ __forceinline__ unsigned mapf(float f) {
    int b = __float_as_int(f);
    return (unsigned)(b ^ ((b >> 31) | 0x80000000));
}
__device__ __forceinline__ float unmapf(unsigned u) {
    int b = (u & 0x80000000u) ? (int)(u ^ 0x80000000u) : ~(int)u;
    return __int_as_float(b);
}

struct Rel {
    const float* xsrc;   // [n_src, D_IN]
    const int* edges;    // packed, bucket-partitioned per 16K chunk
    const int* boff;     // [NBLKS][BOFF_STRIDE] chunk-relative bucket starts
    const float* W;      // [D_IN*32]
    const float* b;      // [32]
    const float* Wroot;  // [D_IN*32]
};

// ---------------- bucket sort (block-local, no global atomics) ----------------

__global__ __launch_bounds__(256) void bucket_sort_kernel(
    const int* __restrict__ e0, const int* __restrict__ e1, const int* __restrict__ e2,
    const int* __restrict__ e3, const int* __restrict__ e4,
    int* __restrict__ edges_out, int* __restrict__ boff)
{
    int j = blockIdx.x, rel = blockIdx.y, tid = threadIdx.x;
    const int* ei = (rel == 0) ? e0 : (rel == 1) ? e1 : (rel == 2) ? e2 : (rel == 3) ? e3 : e4;
    int nb = (rel == 2 || rel == 3) ? NBKT_B : NBKT_S;

    __shared__ int hist[BOFF_STRIDE];
    __shared__ int part[256];

    for (int i = tid; i < BOFF_STRIDE; i += 256) hist[i] = 0;
    __syncthreads();

    int es = j * CHUNK, ee = min(EE, es + CHUNK);
    for (int e = es + tid; e < ee; e += 256)
        atomicAdd(&hist[ei[EE + e] >> BSHIFT], 1);
    __syncthreads();

    // exclusive scan of hist[0..nb); hist[nb] = chunk count
    const int C = 7;  // 256*7 >= 1564
    int vals[C];
    int lsum = 0;
    #pragma unroll
    for (int c = 0; c < C; ++c) {
        int i = tid * C + c;
        int v = (i < nb) ? hist[i] : 0;
        vals[c] = v; lsum += v;
    }
    part[tid] = lsum;
    __syncthreads();
    for (int off = 1; off < 256; off <<= 1) {
        int t = (tid >= off) ? part[tid - off] : 0;
        __syncthreads();
        part[tid] += t;
        __syncthreads();
    }
    int run = (tid > 0) ? part[tid - 1] : 0;
    #pragma unroll
    for (int c = 0; c < C; ++c) {
        int i = tid * C + c;
        if (i < nb) hist[i] = run;
        run += vals[c];
    }
    __syncthreads();
    if (tid == 0) hist[nb] = ee - es;
    __syncthreads();

    int* bo = boff + (rel * NBLKS + j) * BOFF_STRIDE;
    for (int i = tid; i <= nb; i += 256) bo[i] = hist[i];
    __syncthreads();  // hist doubles as cursor array below

    int* eo = edges_out + rel * EPAD + j * CHUNK;
    for (int e = es + tid; e < ee; e += 256) {
        int s = ei[e], d = ei[EE + e];
        int pos = atomicAdd(&hist[d >> BSHIFT], 1);
        eo[pos] = ((d & (BSIZE - 1)) << SLOT_SHIFT) | s;
    }
}

// ---------------- fused layer (bucket-LDS aggregation) ----------------
// AGGR: 0=add, 1=mean, 2=max

template <int D_IN, int AGGR>
__device__ __forceinline__ void do_rel(const Rel& R, int bkt, int lane32, int pairidx,
                                       int w, int g, int tid, float* sW, float* accF,
                                       int* cnt, float (&o)[8])
{
    unsigned* accU = (unsigned*)accF;
    __syncthreads();  // protect previous phase's sW/acc readers
    for (int i = tid; i < D_IN * 32; i += 256) sW[i] = R.W[i];
    for (int i = tid; i < BSIZE * 32; i += 256) {
        if (AGGR == 2) accU[i] = MAXINIT; else accF[i] = 0.f;
    }
    if (AGGR == 1 && tid < BSIZE) cnt[tid] = 0;
    __syncthreads();

    // edge scan: wave w handles chunks w, w+4, ...; half-waves take alternating edges
    for (int j = w; j < NBLKS; j += 4) {
        const int* bo = R.boff + j * BOFF_STRIDE + bkt;
        int s0 = bo[0], s1 = bo[1];
        const int* ep = R.edges + j * CHUNK;
        for (int e = s0 + pairidx; e < s1; e += 2) {
            int p = ep[e];
            int slot = p >> SLOT_SHIFT, s = p & SRC_MASK;
            float v = (lane32 < D_IN) ? R.xsrc[s * D_IN + lane32] : 0.f;
            if (AGGR == 2) {
                if (lane32 < D_IN) atomicMax(&accU[slot * 32 + lane32], mapf(v));
            } else {
                if (lane32 < D_IN) atomicAdd(&accF[slot * 32 + lane32], v);
            }
            if (AGGR == 1 && lane32 == 0) atomicAdd(&cnt[slot], 1);
        }
    }
    __syncthreads();

    // matmul: group g owns slots g*8 .. g*8+7
    #pragma unroll
    for (int k = 0; k < 8; ++k) {
        int slot = g * 8 + k;
        float a;
        if (AGGR == 2) {
            unsigned u = accU[slot * 32 + lane32];
            a = (u == MAXINIT) ? 0.f : unmapf(u);
        } else {
            a = accF[slot * 32 + lane32];
        }
        if (AGGR == 1) a *= 1.f / (float)max(cnt[slot], 1);
        #pragma unroll
        for (int kk = 0; kk < D_IN; ++kk)
            o[k] = fmaf(__shfl(a, kk, 32), sW[kk * 32 + lane32], o[k]);
    }
}

template <int D_IN, int NREL, bool RES, bool RELU, int A0, int A1, int A2>
__global__ __launch_bounds__(256) void layer_kernel(
    Rel r0, Rel r1, Rel r2,
    const float* __restrict__ x_dst, float* __restrict__ outp, int n_dst)
{
    __shared__ float sW[32 * 32];
    __shared__ float accF[BSIZE * 32];
    __shared__ int cnt[BSIZE];

    int tid = threadIdx.x;
    int lane32 = tid & 31, g = tid >> 5;
    int w = tid >> 6, pairidx = (tid >> 5) & 1;
    int bkt = blockIdx.x;
    int node_base = bkt * BSIZE;
    int nnodes = min(BSIZE, n_dst - node_base);

    // phase 0: summed root weights + biases
    for (int i = tid; i < D_IN * 32; i += 256) {
        float wv = r0.Wroot[i];
        if (NREL > 1) wv += r1.Wroot[i];
        if (NREL > 2) wv += r2.Wroot[i];
        sW[i] = wv;
    }
    float bsum = r0.b[lane32];
    if (NREL > 1) bsum += r1.b[lane32];
    if (NREL > 2) bsum += r2.b[lane32];
    __syncthreads();

    float o[8];
    #pragma unroll
    for (int k = 0; k < 8; ++k) {
        int slot = g * 8 + k;
        int node = node_base + slot;
        float xv = (slot < nnodes && lane32 < D_IN) ? x_dst[node * D_IN + lane32] : 0.f;
        float acc = bsum;
        #pragma unroll
        for (int kk = 0; kk < D_IN; ++kk)
            acc = fmaf(__shfl(xv, kk, 32), sW[kk * 32 + lane32], acc);
        if (RES) acc += xv;
        o[k] = acc;
    }

    do_rel<D_IN, A0>(r0, bkt, lane32, pairidx, w, g, tid, sW, accF, cnt, o);
    if constexpr (NREL > 1) do_rel<D_IN, A1>(r1, bkt, lane32, pairidx, w, g, tid, sW, accF, cnt, o);
    if constexpr (NREL > 2) do_rel<D_IN, A2>(r2, bkt, lane32, pairidx, w, g, tid, sW, accF, cnt, o);

    #pragma unroll
    for (int k = 0; k < 8; ++k) {
        int slot = g * 8 + k;
        if (slot < nnodes) {
            float v = RELU ? fmaxf(o[k], 0.f) : o[k];
            outp[(node_base + slot) * 32 + lane32] = v;
        }
    }
}

// ---------------- host ----------------

static inline char* alignp(char* p, size_t a) {
    return (char*)(((uintptr_t)p + a - 1) & ~(a - 1));
}

extern "C" void kernel_launch(void* const* d_in, const int* in_sizes, int n_in,
                              void* d_out, int out_size, void* d_ws, size_t ws_size,
                              hipStream_t stream)
{
    const float* x_stroke = (const float*)d_in[0];
    const float* x_brep   = (const float*)d_in[1];
    const int* ei0 = (const int*)d_in[2];
    const int* ei1 = (const int*)d_in[3];
    const int* ei2 = (const int*)d_in[4];
    const int* ei3 = (const int*)d_in[5];
    const int* ei4 = (const int*)d_in[6];
    const float* W0_rel  = (const float*)d_in[7];
    const float* b0_rel  = (const float*)d_in[8];
    const float* W0_root = (const float*)d_in[9];
    const float* Wb_rel  = (const float*)d_in[10];
    const float* bb_rel  = (const float*)d_in[11];
    const float* Wb_root = (const float*)d_in[12];
    float* out = (float*)d_out;

    // workspace layout, 256B-aligned
    char* p = (char*)d_ws;
    int* edges = (int*)alignp(p, 256);           p = (char*)(edges + 5 * EPAD);
    int* boff  = (int*)alignp(p, 256);           p = (char*)(boff + 5 * NBLKS * BOFF_STRIDE);
    float* xs0 = (float*)alignp(p, 256);         p = (char*)(xs0 + NS * 32);
    float* xs1 = (float*)alignp(p, 256);         p = (char*)(xs1 + NS * 32);
    float* xb0 = (float*)alignp(p, 256);         p = (char*)(xb0 + NB * 32);
    float* xb1 = (float*)alignp(p, 256);         p = (char*)(xb1 + NB * 32);

    bucket_sort_kernel<<<dim3(NBLKS, 5), 256, 0, stream>>>(ei0, ei1, ei2, ei3, ei4, edges, boff);

    auto relW = [&](int l, int r) -> const float* {
        return l == 0 ? W0_rel + r * 6 * 32 : Wb_rel + ((l - 1) * 5 + r) * 32 * 32;
    };
    auto relB = [&](int l, int r) -> const float* {
        return l == 0 ? b0_rel + r * 32 : bb_rel + ((l - 1) * 5 + r) * 32;
    };
    auto relWr = [&](int l, int r) -> const float* {
        return l == 0 ? W0_root + r * 6 * 32 : Wb_root + ((l - 1) * 5 + r) * 32 * 32;
    };
    auto mkrel = [&](int l, int r, const float* xsrc) -> Rel {
        Rel R;
        R.xsrc = xsrc;
        R.edges = edges + r * EPAD;
        R.boff = boff + r * NBLKS * BOFF_STRIDE;
        R.W = relW(l, r); R.b = relB(l, r); R.Wroot = relWr(l, r);
        return R;
    };

    // layer 0 (d=6, no residual)
    {
        Rel s0 = mkrel(0, 0, x_stroke), s1 = mkrel(0, 1, x_stroke), s2 = mkrel(0, 4, x_stroke);
        layer_kernel<6, 3, false, false, 1, 0, 2><<<NBKT_S, 256, 0, stream>>>(s0, s1, s2, x_stroke, xs0, NS);
        Rel b0 = mkrel(0, 2, x_stroke), b1 = mkrel(0, 3, x_brep);
        layer_kernel<6, 2, false, false, 1, 2, 0><<<NBKT_B, 256, 0, stream>>>(b0, b1, b1, x_brep, xb0, NB);
    }

    // layers 1..4 (d=32, residual; layer 4 relu -> d_out)
    const float* cs = xs0; const float* cb = xb0;
    float* outs_s[4] = { xs1, xs0, xs1, out };
    float* outs_b[4] = { xb1, xb0, xb1, out + NS * 32 };
    for (int l = 1; l <= 4; ++l) {
        float* os = outs_s[l - 1];
        float* ob = outs_b[l - 1];
        Rel s0 = mkrel(l, 0, cs), s1 = mkrel(l, 1, cs), s2 = mkrel(l, 4, cs);
        Rel b0 = mkrel(l, 2, cs), b1 = mkrel(l, 3, cb);
        if (l < 4) {
            layer_kernel<32, 3, true, false, 1, 0, 2><<<NBKT_S, 256, 0, stream>>>(s0, s1, s2, cs, os, NS);
            layer_kernel<32, 2, true, false, 1, 2, 0><<<NBKT_B, 256, 0, stream>>>(b0, b1, b1, cb, ob, NB);
        } else {
            layer_kernel<32, 3, true, true, 1, 0, 2><<<NBKT_S, 256, 0, stream>>>(s0, s1, s2, cs, os, NS);
            layer_kernel<32, 2, true, true, 1, 2, 0><<<NBKT_B, 256, 0, stream>>>(b0, b1, b1, cb, ob, NB);
        }
        cs = os; cb = ob;
    }
    (void)in_sizes; (void)n_in; (void)out_size; (void)ws_size;
}

// Round 4
// 3184.575 us; speedup vs baseline: 4.6204x; 4.6204x over previous
//
#include <hip/hip_runtime.h>
#include <math.h>

#define NS 100000
#define NB 50000
#define EE 1600000

#define BSHIFT 6
#define BSIZE 64
#define NBKT_S ((NS + BSIZE - 1) / BSIZE)   // 1563
#define NBKT_B ((NB + BSIZE - 1) / BSIZE)   // 782
#define BOFF_STRIDE (NBKT_S + 1)            // 1564
#define CHUNK 16384
#define NBLKS ((EE + CHUNK - 1) / CHUNK)    // 98
#define EPAD (NBLKS * CHUNK)

#define SRC_MASK 0x1FFFF
#define SLOT_SHIFT 17

struct Rel {
    const float* xsrc;   // [n_src, D_IN]
    const int* rs;       // row_start per node, n_dst+1
    const int* srcs;     // dst-sorted src indices, [E]
    const float* W;      // [D_IN*32]
    const float* b;      // [32]
    const float* Wroot;  // [D_IN*32]
};

// ---------------- stage 1: chunked bucket sort (block-local LDS atomics only) ----

__global__ __launch_bounds__(256) void bucket_sort_kernel(
    const int* __restrict__ e0, const int* __restrict__ e1, const int* __restrict__ e2,
    const int* __restrict__ e3, const int* __restrict__ e4,
    int* __restrict__ edges_out, int* __restrict__ boff, int* __restrict__ bcnt)
{
    int j = blockIdx.x, rel = blockIdx.y, tid = threadIdx.x;
    const int* ei = (rel == 0) ? e0 : (rel == 1) ? e1 : (rel == 2) ? e2 : (rel == 3) ? e3 : e4;
    int nb = (rel == 2 || rel == 3) ? NBKT_B : NBKT_S;

    __shared__ int hist[BOFF_STRIDE];
    __shared__ int part[256];

    for (int i = tid; i < BOFF_STRIDE; i += 256) hist[i] = 0;
    __syncthreads();

    int es = j * CHUNK, ee = min(EE, es + CHUNK);
    for (int e = es + tid; e < ee; e += 256)
        atomicAdd(&hist[ei[EE + e] >> BSHIFT], 1);
    __syncthreads();

    // accumulate global per-bucket counts
    for (int i = tid; i < nb; i += 256)
        if (hist[i]) atomicAdd(&bcnt[rel * NBKT_S + i], hist[i]);

    // exclusive scan of hist[0..nb)
    const int C = 7;  // 256*7 >= 1564
    int vals[C];
    int lsum = 0;
    #pragma unroll
    for (int c = 0; c < C; ++c) {
        int i = tid * C + c;
        int v = (i < nb) ? hist[i] : 0;
        vals[c] = v; lsum += v;
    }
    part[tid] = lsum;
    __syncthreads();
    for (int off = 1; off < 256; off <<= 1) {
        int t = (tid >= off) ? part[tid - off] : 0;
        __syncthreads();
        part[tid] += t;
        __syncthreads();
    }
    int run = (tid > 0) ? part[tid - 1] : 0;
    #pragma unroll
    for (int c = 0; c < C; ++c) {
        int i = tid * C + c;
        if (i < nb) hist[i] = run;
        run += vals[c];
    }
    __syncthreads();
    if (tid == 0) hist[nb] = ee - es;
    __syncthreads();

    int* bo = boff + (rel * NBLKS + j) * BOFF_STRIDE;
    for (int i = tid; i <= nb; i += 256) bo[i] = hist[i];
    __syncthreads();  // hist becomes cursor array

    int* eo = edges_out + rel * EPAD + j * CHUNK;
    for (int e = es + tid; e < ee; e += 256) {
        int s = ei[e], d = ei[EE + e];
        int pos = atomicAdd(&hist[d >> BSHIFT], 1);
        eo[pos] = ((d & (BSIZE - 1)) << SLOT_SHIFT) | s;
    }
}

// ---------------- stage 2: per-relation bucket-base exclusive scan ----------------

__global__ __launch_bounds__(1024) void bscan_kernel(const int* __restrict__ bcnt,
                                                     int* __restrict__ bbase)
{
    int rel = blockIdx.x;
    int nb = (rel == 2 || rel == 3) ? NBKT_B : NBKT_S;
    const int* c = bcnt + rel * NBKT_S;
    int* b = bbase + rel * NBKT_S;
    __shared__ int s[1024];
    int tid = threadIdx.x;
    int i0 = tid * 2, i1 = tid * 2 + 1;
    int v0 = (i0 < nb) ? c[i0] : 0;
    int v1 = (i1 < nb) ? c[i1] : 0;
    s[tid] = v0 + v1;
    __syncthreads();
    for (int off = 1; off < 1024; off <<= 1) {
        int t = (tid >= off) ? s[tid - off] : 0;
        __syncthreads();
        s[tid] += t;
        __syncthreads();
    }
    int ex = (tid > 0) ? s[tid - 1] : 0;
    if (i0 < nb) b[i0] = ex;
    if (i1 < nb) b[i1] = ex + v0;
}

// ---------------- stage 3: per-bucket CSR finalize (counting sort, 64 slots) ------

__global__ __launch_bounds__(256) void csr_build_kernel(
    const int* __restrict__ edges_ch, const int* __restrict__ boff,
    const int* __restrict__ bbase, int* __restrict__ edges_csr, int* __restrict__ rs_all)
{
    int bkt = blockIdx.x, rel = blockIdx.y, tid = threadIdx.x;
    int nb = (rel == 2 || rel == 3) ? NBKT_B : NBKT_S;
    if (bkt >= nb) return;
    int nd = (rel == 2 || rel == 3) ? NB : NS;

    const int* ec = edges_ch + rel * EPAD;
    const int* bo = boff + rel * NBLKS * BOFF_STRIDE;
    int base = bbase[rel * NBKT_S + bkt];
    int* rs = rs_all + rel * (NS + 1);

    __shared__ int seg0[NBLKS], seg1[NBLKS];
    __shared__ int cnt[BSIZE], excl[BSIZE + 1];

    if (tid < NBLKS) {
        seg0[tid] = bo[tid * BOFF_STRIDE + bkt];
        seg1[tid] = bo[tid * BOFF_STRIDE + bkt + 1];
    }
    if (tid < BSIZE) cnt[tid] = 0;
    __syncthreads();

    int w = tid >> 6, l = tid & 63;
    for (int j = w; j < NBLKS; j += 4)
        for (int e = seg0[j] + l; e < seg1[j]; e += 64)
            atomicAdd(&cnt[(ec[j * CHUNK + e] >> SLOT_SHIFT) & (BSIZE - 1)], 1);
    __syncthreads();

    if (tid == 0) {
        int run = 0;
        for (int i = 0; i < BSIZE; ++i) { excl[i] = run; run += cnt[i]; }
        excl[BSIZE] = run;
    }
    __syncthreads();

    int node = bkt * BSIZE + tid;
    if (tid < BSIZE && node < nd) rs[node] = base + excl[tid];
    if (bkt == nb - 1 && tid == 0) rs[nd] = base + excl[BSIZE];

    if (tid < BSIZE) cnt[tid] = base + excl[tid];   // cursors
    __syncthreads();

    int* outp = edges_csr + rel * EE;
    for (int j = w; j < NBLKS; j += 4)
        for (int e = seg0[j] + l; e < seg1[j]; e += 64) {
            int p = ec[j * CHUNK + e];
            int pos = atomicAdd(&cnt[(p >> SLOT_SHIFT) & (BSIZE - 1)], 1);
            outp[pos] = p & SRC_MASK;
        }
}

// ---------------- fused layer: 1 node per wave64, register accumulation ----------
// AGGR: 0=add, 1=mean, 2=max

template <int D_IN, int AGGR>
__device__ __forceinline__ void do_rel(const Rel& R, int node, int dim, int half,
                                       int tid, float* sW, float& out_acc)
{
    __syncthreads();  // protect previous phase's sW readers
    for (int i = tid; i < D_IN * 32; i += 256) sW[i] = R.W[i];
    __syncthreads();

    int s0 = R.rs[node], s1 = R.rs[node + 1];
    int nE = s1 - s0;
    float acc = (AGGR == 2) ? -INFINITY : 0.f;
    int li = tid & 63;

    for (int bstart = 0; bstart < nE; bstart += 64) {
        int rem = nE - bstart;
        int idx = R.srcs[s0 + bstart + min(li, rem - 1)];   // coalesced batch of indices
        int m = min(rem, 64);
        #pragma unroll 4
        for (int t = half; t < m; t += 2) {
            int s = __shfl(idx, t, 64);
            float v = (dim < D_IN) ? R.xsrc[s * D_IN + dim] : 0.f;
            if (AGGR == 2) acc = fmaxf(acc, v); else acc += v;
        }
    }
    // combine the two halves of the wave
    float other = __shfl_xor(acc, 32, 64);
    acc = (AGGR == 2) ? fmaxf(acc, other) : (acc + other);
    if (AGGR == 1) acc *= 1.f / (float)max(nE, 1);
    if (AGGR == 2 && nE == 0) acc = 0.f;

    #pragma unroll
    for (int kk = 0; kk < D_IN; ++kk)
        out_acc = fmaf(__shfl(acc, kk, 32), sW[kk * 32 + dim], out_acc);
}

template <int D_IN, int NREL, bool RES, bool RELU, int A0, int A1, int A2>
__global__ __launch_bounds__(256) void layer_kernel(
    Rel r0, Rel r1, Rel r2,
    const float* __restrict__ x_dst, float* __restrict__ outp)
{
    __shared__ float sW[32 * 32];
    int tid = threadIdx.x;
    int dim = tid & 31;
    int half = (tid >> 5) & 1;
    int node = blockIdx.x * 4 + (tid >> 6);

    for (int i = tid; i < D_IN * 32; i += 256) {
        float wv = r0.Wroot[i];
        if (NREL > 1) wv += r1.Wroot[i];
        if (NREL > 2) wv += r2.Wroot[i];
        sW[i] = wv;
    }
    float out_acc = r0.b[dim];
    if (NREL > 1) out_acc += r1.b[dim];
    if (NREL > 2) out_acc += r2.b[dim];
    __syncthreads();

    float xv = (dim < D_IN) ? x_dst[node * D_IN + dim] : 0.f;
    #pragma unroll
    for (int kk = 0; kk < D_IN; ++kk)
        out_acc = fmaf(__shfl(xv, kk, 32), sW[kk * 32 + dim], out_acc);
    if (RES) out_acc += xv;

    do_rel<D_IN, A0>(r0, node, dim, half, tid, sW, out_acc);
    if constexpr (NREL > 1) do_rel<D_IN, A1>(r1, node, dim, half, tid, sW, out_acc);
    if constexpr (NREL > 2) do_rel<D_IN, A2>(r2, node, dim, half, tid, sW, out_acc);

    if (RELU) out_acc = fmaxf(out_acc, 0.f);
    if (half == 0) outp[node * 32 + dim] = out_acc;
}

// ---------------- host ----------------

static inline char* alignp(char* p, size_t a) {
    return (char*)(((uintptr_t)p + a - 1) & ~(a - 1));
}

extern "C" void kernel_launch(void* const* d_in, const int* in_sizes, int n_in,
                              void* d_out, int out_size, void* d_ws, size_t ws_size,
                              hipStream_t stream)
{
    const float* x_stroke = (const float*)d_in[0];
    const float* x_brep   = (const float*)d_in[1];
    const int* ei0 = (const int*)d_in[2];
    const int* ei1 = (const int*)d_in[3];
    const int* ei2 = (const int*)d_in[4];
    const int* ei3 = (const int*)d_in[5];
    const int* ei4 = (const int*)d_in[6];
    const float* W0_rel  = (const float*)d_in[7];
    const float* b0_rel  = (const float*)d_in[8];
    const float* W0_root = (const float*)d_in[9];
    const float* Wb_rel  = (const float*)d_in[10];
    const float* bb_rel  = (const float*)d_in[11];
    const float* Wb_root = (const float*)d_in[12];
    float* out = (float*)d_out;

    // ---- workspace layout ----
    // Region A: build-phase arrays, overlaid by feature ping-pong buffers afterwards.
    char* A = alignp((char*)d_ws, 256);
    int* edges_ch = (int*)A;                                              // 5*EPAD
    int* boff = (int*)alignp((char*)(edges_ch + 5 * EPAD), 256);          // 5*NBLKS*BOFF_STRIDE
    int* bcnt = (int*)alignp((char*)(boff + 5 * NBLKS * BOFF_STRIDE), 256); // 5*NBKT_S
    int* bbase = (int*)alignp((char*)(bcnt + 5 * NBKT_S), 256);           // 5*NBKT_S
    char* buildEnd = (char*)(bbase + 5 * NBKT_S);

    float* xs0 = (float*)A;               // overlay (features live after build)
    float* xs1 = xs0 + (size_t)NS * 32;
    float* xb0 = xs1 + (size_t)NS * 32;
    float* xb1 = xb0 + (size_t)NB * 32;
    char* featEnd = (char*)(xb1 + (size_t)NB * 32);

    char* Aend = (buildEnd > featEnd) ? buildEnd : featEnd;
    int* edges_csr = (int*)alignp(Aend, 256);                             // 5*EE
    int* rs_all = (int*)alignp((char*)(edges_csr + (size_t)5 * EE), 256); // 5*(NS+1)

    // ---- build ----
    hipMemsetAsync(bcnt, 0, 5 * NBKT_S * sizeof(int), stream);
    bucket_sort_kernel<<<dim3(NBLKS, 5), 256, 0, stream>>>(ei0, ei1, ei2, ei3, ei4,
                                                           edges_ch, boff, bcnt);
    bscan_kernel<<<5, 1024, 0, stream>>>(bcnt, bbase);
    csr_build_kernel<<<dim3(NBKT_S, 5), 256, 0, stream>>>(edges_ch, boff, bbase,
                                                          edges_csr, rs_all);

    // ---- weights ----
    auto relW = [&](int l, int r) -> const float* {
        return l == 0 ? W0_rel + r * 6 * 32 : Wb_rel + ((l - 1) * 5 + r) * 32 * 32;
    };
    auto relB = [&](int l, int r) -> const float* {
        return l == 0 ? b0_rel + r * 32 : bb_rel + ((l - 1) * 5 + r) * 32;
    };
    auto relWr = [&](int l, int r) -> const float* {
        return l == 0 ? W0_root + r * 6 * 32 : Wb_root + ((l - 1) * 5 + r) * 32 * 32;
    };
    auto mkrel = [&](int l, int r, const float* xsrc) -> Rel {
        Rel R;
        R.xsrc = xsrc;
        R.rs = rs_all + r * (NS + 1);
        R.srcs = edges_csr + (size_t)r * EE;
        R.W = relW(l, r); R.b = relB(l, r); R.Wroot = relWr(l, r);
        return R;
    };

    const int GS = NS / 4, GB = NB / 4;

    // layer 0 (d=6, no residual)
    {
        Rel s0 = mkrel(0, 0, x_stroke), s1 = mkrel(0, 1, x_stroke), s2 = mkrel(0, 4, x_stroke);
        layer_kernel<6, 3, false, false, 1, 0, 2><<<GS, 256, 0, stream>>>(s0, s1, s2, x_stroke, xs0);
        Rel b0 = mkrel(0, 2, x_stroke), b1 = mkrel(0, 3, x_brep);
        layer_kernel<6, 2, false, false, 1, 2, 0><<<GB, 256, 0, stream>>>(b0, b1, b1, x_brep, xb0);
    }

    // layers 1..4 (d=32, residual; layer 4 relu -> d_out)
    const float* cs = xs0; const float* cb = xb0;
    float* outs_s[4] = { xs1, xs0, xs1, out };
    float* outs_b[4] = { xb1, xb0, xb1, out + (size_t)NS * 32 };
    for (int l = 1; l <= 4; ++l) {
        float* os = outs_s[l - 1];
        float* ob = outs_b[l - 1];
        Rel s0 = mkrel(l, 0, cs), s1 = mkrel(l, 1, cs), s2 = mkrel(l, 4, cs);
        Rel b0 = mkrel(l, 2, cs), b1 = mkrel(l, 3, cb);
        if (l < 4) {
            layer_kernel<32, 3, true, false, 1, 0, 2><<<GS, 256, 0, stream>>>(s0, s1, s2, cs, os);
            layer_kernel<32, 2, true, false, 1, 2, 0><<<GB, 256, 0, stream>>>(b0, b1, b1, cb, ob);
        } else {
            layer_kernel<32, 3, true, true, 1, 0, 2><<<GS, 256, 0, stream>>>(s0, s1, s2, cs, os);
            layer_kernel<32, 2, true, true, 1, 2, 0><<<GB, 256, 0, stream>>>(b0, b1, b1, cb, ob);
        }
        cs = os; cb = ob;
    }
    (void)in_sizes; (void)n_in; (void)out_size; (void)ws_size;
}

// Round 6
// 2170.415 us; speedup vs baseline: 6.7794x; 1.4673x over previous
//
#include <hip/hip_runtime.h>
#include <math.h>

#define NS 100000
#define NB 50000
#define EE 1600000

#define BSHIFT 6
#define BSIZE 64
#define NBKT_S ((NS + BSIZE - 1) / BSIZE)   // 1563
#define NBKT_B ((NB + BSIZE - 1) / BSIZE)   // 782
#define BOFF_STRIDE (NBKT_S + 1)            // 1564
#define CHUNK 16384
#define NBLKS ((EE + CHUNK - 1) / CHUNK)    // 98
#define EPAD (NBLKS * CHUNK)

#define SRC_MASK 0x1FFFF
#define SLOT_SHIFT 17

struct Rel {
    const float* xsrc;   // [n_src, D_IN]
    const int* rs;       // row_start per node, n_dst+1
    const int* srcs;     // dst-sorted src indices, [E]
    const float* W;      // [D_IN*32]
    const float* b;      // [32]
    const float* Wroot;  // [D_IN*32]
};

// ---------------- stage 1: chunked bucket sort (block-local LDS atomics only) ----

__global__ __launch_bounds__(256) void bucket_sort_kernel(
    const int* __restrict__ e0, const int* __restrict__ e1, const int* __restrict__ e2,
    const int* __restrict__ e3, const int* __restrict__ e4,
    int* __restrict__ edges_out, int* __restrict__ boff, int* __restrict__ bcnt)
{
    int j = blockIdx.x, rel = blockIdx.y, tid = threadIdx.x;
    const int* ei = (rel == 0) ? e0 : (rel == 1) ? e1 : (rel == 2) ? e2 : (rel == 3) ? e3 : e4;
    int nb = (rel == 2 || rel == 3) ? NBKT_B : NBKT_S;

    __shared__ int hist[BOFF_STRIDE];
    __shared__ int part[256];

    for (int i = tid; i < BOFF_STRIDE; i += 256) hist[i] = 0;
    __syncthreads();

    int es = j * CHUNK, ee = min(EE, es + CHUNK);
    for (int e = es + tid; e < ee; e += 256)
        atomicAdd(&hist[ei[EE + e] >> BSHIFT], 1);
    __syncthreads();

    for (int i = tid; i < nb; i += 256)
        if (hist[i]) atomicAdd(&bcnt[rel * NBKT_S + i], hist[i]);

    const int C = 7;  // 256*7 >= 1564
    int vals[C];
    int lsum = 0;
    #pragma unroll
    for (int c = 0; c < C; ++c) {
        int i = tid * C + c;
        int v = (i < nb) ? hist[i] : 0;
        vals[c] = v; lsum += v;
    }
    part[tid] = lsum;
    __syncthreads();
    for (int off = 1; off < 256; off <<= 1) {
        int t = (tid >= off) ? part[tid - off] : 0;
        __syncthreads();
        part[tid] += t;
        __syncthreads();
    }
    int run = (tid > 0) ? part[tid - 1] : 0;
    #pragma unroll
    for (int c = 0; c < C; ++c) {
        int i = tid * C + c;
        if (i < nb) hist[i] = run;
        run += vals[c];
    }
    __syncthreads();
    if (tid == 0) hist[nb] = ee - es;
    __syncthreads();

    int* bo = boff + (rel * NBLKS + j) * BOFF_STRIDE;
    for (int i = tid; i <= nb; i += 256) bo[i] = hist[i];
    __syncthreads();  // hist becomes cursor array

    int* eo = edges_out + rel * EPAD + j * CHUNK;
    for (int e = es + tid; e < ee; e += 256) {
        int s = ei[e], d = ei[EE + e];
        int pos = atomicAdd(&hist[d >> BSHIFT], 1);
        eo[pos] = ((d & (BSIZE - 1)) << SLOT_SHIFT) | s;
    }
}

// ---------------- stage 2: per-relation bucket-base exclusive scan ----------------

__global__ __launch_bounds__(1024) void bscan_kernel(const int* __restrict__ bcnt,
                                                     int* __restrict__ bbase)
{
    int rel = blockIdx.x;
    int nb = (rel == 2 || rel == 3) ? NBKT_B : NBKT_S;
    const int* c = bcnt + rel * NBKT_S;
    int* b = bbase + rel * NBKT_S;
    __shared__ int s[1024];
    int tid = threadIdx.x;
    int i0 = tid * 2, i1 = tid * 2 + 1;
    int v0 = (i0 < nb) ? c[i0] : 0;
    int v1 = (i1 < nb) ? c[i1] : 0;
    s[tid] = v0 + v1;
    __syncthreads();
    for (int off = 1; off < 1024; off <<= 1) {
        int t = (tid >= off) ? s[tid - off] : 0;
        __syncthreads();
        s[tid] += t;
        __syncthreads();
    }
    int ex = (tid > 0) ? s[tid - 1] : 0;
    if (i0 < nb) b[i0] = ex;
    if (i1 < nb) b[i1] = ex + v0;
}

// ---------------- stage 3: per-bucket CSR finalize (counting sort, 64 slots) ------

__global__ __launch_bounds__(256) void csr_build_kernel(
    const int* __restrict__ edges_ch, const int* __restrict__ boff,
    const int* __restrict__ bbase, int* __restrict__ edges_csr, int* __restrict__ rs_all)
{
    int bkt = blockIdx.x, rel = blockIdx.y, tid = threadIdx.x;
    int nb = (rel == 2 || rel == 3) ? NBKT_B : NBKT_S;
    if (bkt >= nb) return;
    int nd = (rel == 2 || rel == 3) ? NB : NS;

    const int* ec = edges_ch + rel * EPAD;
    const int* bo = boff + rel * NBLKS * BOFF_STRIDE;
    int base = bbase[rel * NBKT_S + bkt];
    int* rs = rs_all + rel * (NS + 1);

    __shared__ int seg0[NBLKS], seg1[NBLKS];
    __shared__ int cnt[BSIZE], excl[BSIZE + 1];

    if (tid < NBLKS) {
        seg0[tid] = bo[tid * BOFF_STRIDE + bkt];
        seg1[tid] = bo[tid * BOFF_STRIDE + bkt + 1];
    }
    if (tid < BSIZE) cnt[tid] = 0;
    __syncthreads();

    int w = tid >> 6, l = tid & 63;
    for (int j = w; j < NBLKS; j += 4)
        for (int e = seg0[j] + l; e < seg1[j]; e += 64)
            atomicAdd(&cnt[(ec[j * CHUNK + e] >> SLOT_SHIFT) & (BSIZE - 1)], 1);
    __syncthreads();

    if (tid == 0) {
        int run = 0;
        for (int i = 0; i < BSIZE; ++i) { excl[i] = run; run += cnt[i]; }
        excl[BSIZE] = run;
    }
    __syncthreads();

    int node = bkt * BSIZE + tid;
    if (tid < BSIZE && node < nd) rs[node] = base + excl[tid];
    if (bkt == nb - 1 && tid == 0) rs[nd] = base + excl[BSIZE];

    if (tid < BSIZE) cnt[tid] = base + excl[tid];   // cursors
    __syncthreads();

    int* outp = edges_csr + rel * EE;
    for (int j = w; j < NBLKS; j += 4)
        for (int e = seg0[j] + l; e < seg1[j]; e += 64) {
            int p = ec[j * CHUNK + e];
            int pos = atomicAdd(&cnt[(p >> SLOT_SHIFT) & (BSIZE - 1)], 1);
            outp[pos] = p & SRC_MASK;
        }
}

// ---------------- gather helpers: 8 rows per load instruction ----------------
// Wave = 8 octets x 8 lanes. Octet o loads edges {o, 8+o, ...}; within an octet,
// lane reads a float4 (D=32) or scalar (D=6) slice of the row -> 128B coalesced.
// ALL __shfl broadcasts execute with the FULL wave active (divergence-free);
// only the dependent load/accumulate is predicated. Reading a shuffle from an
// inactive lane is undefined on CDNA (this was R5's correctness bug).

template <int AGGR>
__device__ __forceinline__ float4 gather32(const float* __restrict__ xsrc,
                                           const int* __restrict__ srcs,
                                           int s0, int s1, int li, int oct, int qd)
{
    float init = (AGGR == 2) ? -INFINITY : 0.f;
    float4 acc; acc.x = acc.y = acc.z = acc.w = init;
    int nE = s1 - s0;
    for (int bs = 0; bs < nE; bs += 64) {
        int rem = nE - bs;
        int m = rem < 64 ? rem : 64;
        int idx = srcs[s0 + bs + (li < m ? li : m - 1)];
        #pragma unroll
        for (int g = 0; g < 8; ++g) {
            int t = g * 8 + oct;
            int s = __shfl(idx, t, 64);          // full-wave shuffle
            if (t < m) {
                float4 v = *reinterpret_cast<const float4*>(&xsrc[s * 32 + qd]);
                if (AGGR == 2) {
                    acc.x = fmaxf(acc.x, v.x); acc.y = fmaxf(acc.y, v.y);
                    acc.z = fmaxf(acc.z, v.z); acc.w = fmaxf(acc.w, v.w);
                } else {
                    acc.x += v.x; acc.y += v.y; acc.z += v.z; acc.w += v.w;
                }
            }
        }
    }
    #pragma unroll
    for (int mask = 8; mask <= 32; mask <<= 1) {
        float ox = __shfl_xor(acc.x, mask, 64);
        float oy = __shfl_xor(acc.y, mask, 64);
        float oz = __shfl_xor(acc.z, mask, 64);
        float ow = __shfl_xor(acc.w, mask, 64);
        if (AGGR == 2) {
            acc.x = fmaxf(acc.x, ox); acc.y = fmaxf(acc.y, oy);
            acc.z = fmaxf(acc.z, oz); acc.w = fmaxf(acc.w, ow);
        } else { acc.x += ox; acc.y += oy; acc.z += oz; acc.w += ow; }
    }
    if (AGGR == 1) {
        float inv = 1.f / (float)max(nE, 1);
        acc.x *= inv; acc.y *= inv; acc.z *= inv; acc.w *= inv;
    }
    if (AGGR == 2 && nE == 0) acc.x = acc.y = acc.z = acc.w = 0.f;
    return acc;
}

template <int AGGR>
__device__ __forceinline__ float gather6(const float* __restrict__ xsrc,
                                         const int* __restrict__ srcs,
                                         int s0, int s1, int li, int oct, int ld)
{
    float acc = (AGGR == 2) ? -INFINITY : 0.f;
    int nE = s1 - s0;
    for (int bs = 0; bs < nE; bs += 64) {
        int rem = nE - bs;
        int m = rem < 64 ? rem : 64;
        int idx = srcs[s0 + bs + (li < m ? li : m - 1)];
        #pragma unroll
        for (int g = 0; g < 8; ++g) {
            int t = g * 8 + oct;
            int s = __shfl(idx, t, 64);          // full-wave shuffle
            if (t < m && ld < 6) {
                float v = xsrc[s * 6 + ld];
                if (AGGR == 2) acc = fmaxf(acc, v); else acc += v;
            }
        }
    }
    #pragma unroll
    for (int mask = 8; mask <= 32; mask <<= 1) {
        float o = __shfl_xor(acc, mask, 64);
        acc = (AGGR == 2) ? fmaxf(acc, o) : (acc + o);
    }
    if (AGGR == 1) acc *= 1.f / (float)max(nE, 1);
    if (AGGR == 2 && nE == 0) acc = 0.f;
    return acc;
}

// matmul: agg-row (replicated octet layout) times W -> scalar per lane (dim=li&31)
__device__ __forceinline__ void mmacc32(const float4& a, const float* sW, int dim, float& mm)
{
    #pragma unroll
    for (int kk = 0; kk < 32; ++kk) {
        float av;
        if ((kk & 3) == 0) av = __shfl(a.x, kk >> 2, 64);
        else if ((kk & 3) == 1) av = __shfl(a.y, kk >> 2, 64);
        else if ((kk & 3) == 2) av = __shfl(a.z, kk >> 2, 64);
        else av = __shfl(a.w, kk >> 2, 64);
        mm = fmaf(av, sW[kk * 32 + dim], mm);
    }
}

__device__ __forceinline__ void mmacc6(float a, const float* sW, int dim, float& mm)
{
    #pragma unroll
    for (int kk = 0; kk < 6; ++kk) {
        float av = __shfl(a, kk, 64);
        mm = fmaf(av, sW[kk * 32 + dim], mm);
    }
}

// ---------------- fused layer: 1 node per wave64 ----------
// AGGR: 0=add, 1=mean, 2=max

template <int D_IN, int NREL, bool RES, bool RELU, int A0, int A1, int A2>
__global__ __launch_bounds__(256, 4) void layer_kernel(
    Rel r0, Rel r1, Rel r2,
    const float* __restrict__ x_dst, float* __restrict__ outp)
{
    __shared__ float sW[NREL][D_IN * 32];
    __shared__ float sWr[D_IN * 32];
    int tid = threadIdx.x;

    for (int i = tid; i < D_IN * 32; i += 256) {
        sW[0][i] = r0.W[i];
        if (NREL > 1) sW[1][i] = r1.W[i];
        if (NREL > 2) sW[2][i] = r2.W[i];
        float wr = r0.Wroot[i];
        if (NREL > 1) wr += r1.Wroot[i];
        if (NREL > 2) wr += r2.Wroot[i];
        sWr[i] = wr;
    }

    int li = tid & 63;
    int node = blockIdx.x * 4 + (tid >> 6);
    int oct = li >> 3;
    int qd = (li & 7) * 4;
    int ld = li & 7;
    int dim = li & 31;

    float mm = r0.b[dim];
    if (NREL > 1) mm += r1.b[dim];
    if (NREL > 2) mm += r2.b[dim];

    int a0 = r0.rs[node], a1 = r0.rs[node + 1];
    int b0 = 0, b1 = 0, c0 = 0, c1 = 0;
    if (NREL > 1) { b0 = r1.rs[node]; b1 = r1.rs[node + 1]; }
    if (NREL > 2) { c0 = r2.rs[node]; c1 = r2.rs[node + 1]; }

    float xv = (dim < D_IN) ? x_dst[node * D_IN + dim] : 0.f;

    __syncthreads();

    if (D_IN == 32) {
        float4 ag0 = gather32<A0>(r0.xsrc, r0.srcs, a0, a1, li, oct, qd);
        float4 ag1, ag2;
        if (NREL > 1) ag1 = gather32<A1>(r1.xsrc, r1.srcs, b0, b1, li, oct, qd);
        if (NREL > 2) ag2 = gather32<A2>(r2.xsrc, r2.srcs, c0, c1, li, oct, qd);
        mmacc32(ag0, sW[0], dim, mm);
        if (NREL > 1) mmacc32(ag1, sW[1], dim, mm);
        if (NREL > 2) mmacc32(ag2, sW[2], dim, mm);
    } else {
        float ag0 = gather6<A0>(r0.xsrc, r0.srcs, a0, a1, li, oct, ld);
        float ag1 = 0.f, ag2 = 0.f;
        if (NREL > 1) ag1 = gather6<A1>(r1.xsrc, r1.srcs, b0, b1, li, oct, ld);
        if (NREL > 2) ag2 = gather6<A2>(r2.xsrc, r2.srcs, c0, c1, li, oct, ld);
        mmacc6(ag0, sW[0], dim, mm);
        if (NREL > 1) mmacc6(ag1, sW[1], dim, mm);
        if (NREL > 2) mmacc6(ag2, sW[2], dim, mm);
    }

    // root term
    #pragma unroll
    for (int kk = 0; kk < D_IN; ++kk)
        mm = fmaf(__shfl(xv, kk, 32), sWr[kk * 32 + dim], mm);
    if (RES) mm += xv;
    if (RELU) mm = fmaxf(mm, 0.f);
    if (li < 32) outp[node * 32 + dim] = mm;
}

// ---------------- host ----------------

static inline char* alignp(char* p, size_t a) {
    return (char*)(((uintptr_t)p + a - 1) & ~(a - 1));
}

extern "C" void kernel_launch(void* const* d_in, const int* in_sizes, int n_in,
                              void* d_out, int out_size, void* d_ws, size_t ws_size,
                              hipStream_t stream)
{
    const float* x_stroke = (const float*)d_in[0];
    const float* x_brep   = (const float*)d_in[1];
    const int* ei0 = (const int*)d_in[2];
    const int* ei1 = (const int*)d_in[3];
    const int* ei2 = (const int*)d_in[4];
    const int* ei3 = (const int*)d_in[5];
    const int* ei4 = (const int*)d_in[6];
    const float* W0_rel  = (const float*)d_in[7];
    const float* b0_rel  = (const float*)d_in[8];
    const float* W0_root = (const float*)d_in[9];
    const float* Wb_rel  = (const float*)d_in[10];
    const float* bb_rel  = (const float*)d_in[11];
    const float* Wb_root = (const float*)d_in[12];
    float* out = (float*)d_out;

    char* A = alignp((char*)d_ws, 256);
    int* edges_ch = (int*)A;                                              // 5*EPAD
    int* boff = (int*)alignp((char*)(edges_ch + 5 * EPAD), 256);
    int* bcnt = (int*)alignp((char*)(boff + 5 * NBLKS * BOFF_STRIDE), 256);
    int* bbase = (int*)alignp((char*)(bcnt + 5 * NBKT_S), 256);
    char* buildEnd = (char*)(bbase + 5 * NBKT_S);

    float* xs0 = (float*)A;               // overlay: features live after build
    float* xs1 = xs0 + (size_t)NS * 32;
    float* xb0 = xs1 + (size_t)NS * 32;
    float* xb1 = xb0 + (size_t)NB * 32;
    char* featEnd = (char*)(xb1 + (size_t)NB * 32);

    char* Aend = (buildEnd > featEnd) ? buildEnd : featEnd;
    int* edges_csr = (int*)alignp(Aend, 256);                             // 5*EE
    int* rs_all = (int*)alignp((char*)(edges_csr + (size_t)5 * EE), 256); // 5*(NS+1)

    hipMemsetAsync(bcnt, 0, 5 * NBKT_S * sizeof(int), stream);
    bucket_sort_kernel<<<dim3(NBLKS, 5), 256, 0, stream>>>(ei0, ei1, ei2, ei3, ei4,
                                                           edges_ch, boff, bcnt);
    bscan_kernel<<<5, 1024, 0, stream>>>(bcnt, bbase);
    csr_build_kernel<<<dim3(NBKT_S, 5), 256, 0, stream>>>(edges_ch, boff, bbase,
                                                          edges_csr, rs_all);

    auto relW = [&](int l, int r) -> const float* {
        return l == 0 ? W0_rel + r * 6 * 32 : Wb_rel + ((l - 1) * 5 + r) * 32 * 32;
    };
    auto relB = [&](int l, int r) -> const float* {
        return l == 0 ? b0_rel + r * 32 : bb_rel + ((l - 1) * 5 + r) * 32;
    };
    auto relWr = [&](int l, int r) -> const float* {
        return l == 0 ? W0_root + r * 6 * 32 : Wb_root + ((l - 1) * 5 + r) * 32 * 32;
    };
    auto mkrel = [&](int l, int r, const float* xsrc) -> Rel {
        Rel R;
        R.xsrc = xsrc;
        R.rs = rs_all + r * (NS + 1);
        R.srcs = edges_csr + (size_t)r * EE;
        R.W = relW(l, r); R.b = relB(l, r); R.Wroot = relWr(l, r);
        return R;
    };

    const int GS = NS / 4, GB = NB / 4;

    // layer 0 (d=6, no residual)
    {
        Rel s0 = mkrel(0, 0, x_stroke), s1 = mkrel(0, 1, x_stroke), s2 = mkrel(0, 4, x_stroke);
        layer_kernel<6, 3, false, false, 1, 0, 2><<<GS, 256, 0, stream>>>(s0, s1, s2, x_stroke, xs0);
        Rel b0 = mkrel(0, 2, x_stroke), b1 = mkrel(0, 3, x_brep);
        layer_kernel<6, 2, false, false, 1, 2, 0><<<GB, 256, 0, stream>>>(b0, b1, b1, x_brep, xb0);
    }

    // layers 1..4 (d=32, residual; layer 4 relu -> d_out)
    const float* cs = xs0; const float* cb = xb0;
    float* outs_s[4] = { xs1, xs0, xs1, out };
    float* outs_b[4] = { xb1, xb0, xb1, out + (size_t)NS * 32 };
    for (int l = 1; l <= 4; ++l) {
        float* os = outs_s[l - 1];
        float* ob = outs_b[l - 1];
        Rel s0 = mkrel(l, 0, cs), s1 = mkrel(l, 1, cs), s2 = mkrel(l, 4, cs);
        Rel b0 = mkrel(l, 2, cs), b1 = mkrel(l, 3, cb);
        if (l < 4) {
            layer_kernel<32, 3, true, false, 1, 0, 2><<<GS, 256, 0, stream>>>(s0, s1, s2, cs, os);
            layer_kernel<32, 2, true, false, 1, 2, 0><<<GB, 256, 0, stream>>>(b0, b1, b1, cb, ob);
        } else {
            layer_kernel<32, 3, true, true, 1, 0, 2><<<GS, 256, 0, stream>>>(s0, s1, s2, cs, os);
            layer_kernel<32, 2, true, true, 1, 2, 0><<<GB, 256, 0, stream>>>(b0, b1, b1, cb, ob);
        }
        cs = os; cb = ob;
    }
    (void)in_sizes; (void)n_in; (void)out_size; (void)ws_size;
}

// Round 7
// 1318.044 us; speedup vs baseline: 11.1636x; 1.6467x over previous
//
#include <hip/hip_runtime.h>
#include <math.h>

#define NS 100000
#define NB 50000
#define EE 1600000

#define BSHIFT 6
#define BSIZE 64
#define NBKT_S ((NS + BSIZE - 1) / BSIZE)   // 1563
#define NBKT_B ((NB + BSIZE - 1) / BSIZE)   // 782
#define BOFF_STRIDE (NBKT_S + 1)            // 1564
#define CHUNK 16384
#define NBLKS ((EE + CHUNK - 1) / CHUNK)    // 98
#define EPAD (NBLKS * CHUNK)

#define SRC_MASK 0x1FFFF
#define SLOT_SHIFT 17

// ---------------- stage 1: chunked bucket sort (block-local LDS atomics only) ----

__global__ __launch_bounds__(256) void bucket_sort_kernel(
    const int* __restrict__ e0, const int* __restrict__ e1, const int* __restrict__ e2,
    const int* __restrict__ e3, const int* __restrict__ e4,
    int* __restrict__ edges_out, int* __restrict__ boff, int* __restrict__ bcnt)
{
    int j = blockIdx.x, rel = blockIdx.y, tid = threadIdx.x;
    const int* ei = (rel == 0) ? e0 : (rel == 1) ? e1 : (rel == 2) ? e2 : (rel == 3) ? e3 : e4;
    int nb = (rel == 2 || rel == 3) ? NBKT_B : NBKT_S;

    __shared__ int hist[BOFF_STRIDE];
    __shared__ int part[256];

    for (int i = tid; i < BOFF_STRIDE; i += 256) hist[i] = 0;
    __syncthreads();

    int es = j * CHUNK, ee = min(EE, es + CHUNK);
    for (int e = es + tid; e < ee; e += 256)
        atomicAdd(&hist[ei[EE + e] >> BSHIFT], 1);
    __syncthreads();

    for (int i = tid; i < nb; i += 256)
        if (hist[i]) atomicAdd(&bcnt[rel * NBKT_S + i], hist[i]);

    const int C = 7;  // 256*7 >= 1564
    int vals[C];
    int lsum = 0;
    #pragma unroll
    for (int c = 0; c < C; ++c) {
        int i = tid * C + c;
        int v = (i < nb) ? hist[i] : 0;
        vals[c] = v; lsum += v;
    }
    part[tid] = lsum;
    __syncthreads();
    for (int off = 1; off < 256; off <<= 1) {
        int t = (tid >= off) ? part[tid - off] : 0;
        __syncthreads();
        part[tid] += t;
        __syncthreads();
    }
    int run = (tid > 0) ? part[tid - 1] : 0;
    #pragma unroll
    for (int c = 0; c < C; ++c) {
        int i = tid * C + c;
        if (i < nb) hist[i] = run;
        run += vals[c];
    }
    __syncthreads();
    if (tid == 0) hist[nb] = ee - es;
    __syncthreads();

    int* bo = boff + (rel * NBLKS + j) * BOFF_STRIDE;
    for (int i = tid; i <= nb; i += 256) bo[i] = hist[i];
    __syncthreads();  // hist becomes cursor array

    int* eo = edges_out + rel * EPAD + j * CHUNK;
    for (int e = es + tid; e < ee; e += 256) {
        int s = ei[e], d = ei[EE + e];
        int pos = atomicAdd(&hist[d >> BSHIFT], 1);
        eo[pos] = ((d & (BSIZE - 1)) << SLOT_SHIFT) | s;
    }
}

// ---------------- stage 2: per-relation bucket-base exclusive scan ----------------

__global__ __launch_bounds__(1024) void bscan_kernel(const int* __restrict__ bcnt,
                                                     int* __restrict__ bbase)
{
    int rel = blockIdx.x;
    int nb = (rel == 2 || rel == 3) ? NBKT_B : NBKT_S;
    const int* c = bcnt + rel * NBKT_S;
    int* b = bbase + rel * NBKT_S;
    __shared__ int s[1024];
    int tid = threadIdx.x;
    int i0 = tid * 2, i1 = tid * 2 + 1;
    int v0 = (i0 < nb) ? c[i0] : 0;
    int v1 = (i1 < nb) ? c[i1] : 0;
    s[tid] = v0 + v1;
    __syncthreads();
    for (int off = 1; off < 1024; off <<= 1) {
        int t = (tid >= off) ? s[tid - off] : 0;
        __syncthreads();
        s[tid] += t;
        __syncthreads();
    }
    int ex = (tid > 0) ? s[tid - 1] : 0;
    if (i0 < nb) b[i0] = ex;
    if (i1 < nb) b[i1] = ex + v0;
}

// ---------------- stage 3: per-bucket CSR finalize (counting sort, 64 slots) ------

__global__ __launch_bounds__(256) void csr_build_kernel(
    const int* __restrict__ edges_ch, const int* __restrict__ boff,
    const int* __restrict__ bbase, int* __restrict__ edges_csr, int* __restrict__ rs_all)
{
    int bkt = blockIdx.x, rel = blockIdx.y, tid = threadIdx.x;
    int nb = (rel == 2 || rel == 3) ? NBKT_B : NBKT_S;
    if (bkt >= nb) return;
    int nd = (rel == 2 || rel == 3) ? NB : NS;

    const int* ec = edges_ch + rel * EPAD;
    const int* bo = boff + rel * NBLKS * BOFF_STRIDE;
    int base = bbase[rel * NBKT_S + bkt];
    int* rs = rs_all + rel * (NS + 1);

    __shared__ int seg0[NBLKS], seg1[NBLKS];
    __shared__ int cnt[BSIZE], excl[BSIZE + 1];

    if (tid < NBLKS) {
        seg0[tid] = bo[tid * BOFF_STRIDE + bkt];
        seg1[tid] = bo[tid * BOFF_STRIDE + bkt + 1];
    }
    if (tid < BSIZE) cnt[tid] = 0;
    __syncthreads();

    int w = tid >> 6, l = tid & 63;
    for (int j = w; j < NBLKS; j += 4)
        for (int e = seg0[j] + l; e < seg1[j]; e += 64)
            atomicAdd(&cnt[(ec[j * CHUNK + e] >> SLOT_SHIFT) & (BSIZE - 1)], 1);
    __syncthreads();

    if (tid == 0) {
        int run = 0;
        for (int i = 0; i < BSIZE; ++i) { excl[i] = run; run += cnt[i]; }
        excl[BSIZE] = run;
    }
    __syncthreads();

    int node = bkt * BSIZE + tid;
    if (tid < BSIZE && node < nd) rs[node] = base + excl[tid];
    if (bkt == nb - 1 && tid == 0) rs[nd] = base + excl[BSIZE];

    if (tid < BSIZE) cnt[tid] = base + excl[tid];   // cursors
    __syncthreads();

    int* outp = edges_csr + rel * EE;
    for (int j = w; j < NBLKS; j += 4)
        for (int e = seg0[j] + l; e < seg1[j]; e += 64) {
            int p = ec[j * CHUNK + e];
            int pos = atomicAdd(&cnt[(p >> SLOT_SHIFT) & (BSIZE - 1)], 1);
            outp[pos] = p & SRC_MASK;
        }
}

// ---------------- phase A: per-octet gather aggregation ----------------
// Wave = 8 octets; octet owns one node, its 8 lanes cover the feature row.
// Loop runs to the WAVE-max degree so every __shfl is full-wave (R5 lesson);
// only loads/accumulates are predicated.

struct AggArgs {
    const int* rs[5];
    const int* srcs[5];
    const float* xsrc[5];
    char* agg[5];
    int ndst[5];
    int aggr[5];   // 0=add 1=mean 2=max
};

__device__ __forceinline__ unsigned bfpack(float a, float b) {
    unsigned ua = __float_as_uint(a), ub = __float_as_uint(b);
    ua = (ua + 0x7fffu + ((ua >> 16) & 1u)) >> 16;
    ub = (ub + 0x7fffu + ((ub >> 16) & 1u)) >> 16;
    return ua | (ub << 16);
}

template <int AGGR>
__device__ __forceinline__ float4 gath32(const float* __restrict__ xsrc,
                                         const int* __restrict__ srcs,
                                         int s0, int deg, int md, int li, int l8)
{
    float init = (AGGR == 2) ? -INFINITY : 0.f;
    float4 acc = {init, init, init, init};
    for (int bs = 0; bs < md; bs += 8) {
        int a = s0 + bs + l8;
        int idx = srcs[a < (EE - 1) ? a : (EE - 1)];
        #pragma unroll
        for (int j = 0; j < 8; ++j) {
            int s = __shfl(idx, (li & ~7) + j, 64);       // full-wave
            if (bs + j < deg) {
                float4 v = *reinterpret_cast<const float4*>(xsrc + (size_t)s * 32 + l8 * 4);
                if (AGGR == 2) {
                    acc.x = fmaxf(acc.x, v.x); acc.y = fmaxf(acc.y, v.y);
                    acc.z = fmaxf(acc.z, v.z); acc.w = fmaxf(acc.w, v.w);
                } else {
                    acc.x += v.x; acc.y += v.y; acc.z += v.z; acc.w += v.w;
                }
            }
        }
    }
    return acc;
}

template <int AGGR>
__device__ __forceinline__ float gath6(const float* __restrict__ xsrc,
                                       const int* __restrict__ srcs,
                                       int s0, int deg, int md, int li, int l8)
{
    float acc = (AGGR == 2) ? -INFINITY : 0.f;
    for (int bs = 0; bs < md; bs += 8) {
        int a = s0 + bs + l8;
        int idx = srcs[a < (EE - 1) ? a : (EE - 1)];
        #pragma unroll
        for (int j = 0; j < 8; ++j) {
            int s = __shfl(idx, (li & ~7) + j, 64);       // full-wave
            if (bs + j < deg && l8 < 6) {
                float v = xsrc[(size_t)s * 6 + l8];
                if (AGGR == 2) acc = fmaxf(acc, v); else acc += v;
            }
        }
    }
    return acc;
}

template <int D>
__global__ __launch_bounds__(256, 8) void agg_kernel(AggArgs p)
{
    int rel = blockIdx.y;
    int nd = p.ndst[rel];
    if ((int)blockIdx.x * 32 >= nd) return;
    int tid = threadIdx.x, li = tid & 63, l8 = tid & 7;
    int node = blockIdx.x * 32 + (tid >> 3);
    int nodec = min(node, nd - 1);
    const int* rs = p.rs[rel];
    int s0 = rs[nodec];
    int deg = rs[nodec + 1] - s0;
    if (node >= nd) deg = 0;
    int md = deg;
    md = max(md, __shfl_xor(md, 8, 64));
    md = max(md, __shfl_xor(md, 16, 64));
    md = max(md, __shfl_xor(md, 32, 64));
    const int* srcs = p.srcs[rel];
    const float* xsrc = p.xsrc[rel];
    int aggr = p.aggr[rel];   // uniform per block

    if (D == 32) {
        float4 acc;
        if (aggr == 0)      acc = gath32<0>(xsrc, srcs, s0, deg, md, li, l8);
        else if (aggr == 1) acc = gath32<1>(xsrc, srcs, s0, deg, md, li, l8);
        else                acc = gath32<2>(xsrc, srcs, s0, deg, md, li, l8);
        if (aggr == 1) {
            float inv = 1.f / (float)max(deg, 1);
            acc.x *= inv; acc.y *= inv; acc.z *= inv; acc.w *= inv;
        }
        if (aggr == 2 && deg == 0) { acc.x = acc.y = acc.z = acc.w = 0.f; }
        if (node < nd) {
            uint2 o;
            o.x = bfpack(acc.x, acc.y);
            o.y = bfpack(acc.z, acc.w);
            *reinterpret_cast<uint2*>(p.agg[rel] + (size_t)node * 64 + l8 * 8) = o;
        }
    } else {
        float acc;
        if (aggr == 0)      acc = gath6<0>(xsrc, srcs, s0, deg, md, li, l8);
        else if (aggr == 1) acc = gath6<1>(xsrc, srcs, s0, deg, md, li, l8);
        else                acc = gath6<2>(xsrc, srcs, s0, deg, md, li, l8);
        if (aggr == 1) acc *= 1.f / (float)max(deg, 1);
        if (aggr == 2 && deg == 0) acc = 0.f;
        if (node < nd) {
            float v = (l8 < 6) ? acc : 0.f;
            reinterpret_cast<float*>(p.agg[rel] + (size_t)node * 32)[l8] = v;
        }
    }
}

// ---------------- phase B: dense per-node matmul, weights in VGPRs ----------------
// Wave handles 16 consecutive nodes; agg/x rows read at wave-uniform addresses
// (s_load path) so the k-broadcast is an SGPR operand -> no shuffles, no LDS.

struct MMArgs {
    const char* agg[3];
    const float* W[3];
    const float* Wroot[3];
    const float* b[3];
    const float* xdst;   // NOT restrict: may alias out (in-place residual)
    float* out;
    int ndst;
};

template <int D_IN, int NREL, bool RES, bool RELU>
__global__ __launch_bounds__(256, 3) void mm_kernel(MMArgs p)
{
    int tid = threadIdx.x;
    int li = tid & 63;
    int dim = li & 31;

    float w[NREL][D_IN];
    #pragma unroll
    for (int r = 0; r < NREL; ++r)
        #pragma unroll
        for (int k = 0; k < D_IN; ++k)
            w[r][k] = p.W[r][k * 32 + dim];
    float wr[D_IN];
    #pragma unroll
    for (int k = 0; k < D_IN; ++k) {
        float s = p.Wroot[0][k * 32 + dim];
        if (NREL > 1) s += p.Wroot[1][k * 32 + dim];
        if (NREL > 2) s += p.Wroot[2][k * 32 + dim];
        wr[k] = s;
    }
    float bsum = p.b[0][dim];
    if (NREL > 1) bsum += p.b[1][dim];
    if (NREL > 2) bsum += p.b[2][dim];

    int wg = __builtin_amdgcn_readfirstlane((int)blockIdx.x * 4 + (tid >> 6));
    int nbase = wg * 16;
    if (nbase >= p.ndst) return;
    int nend = min(nbase + 16, p.ndst);

    for (int node = nbase; node < nend; ++node) {
        float mm = bsum;
        #pragma unroll
        for (int r = 0; r < NREL; ++r) {
            if (D_IN == 32) {
                const unsigned* arow = reinterpret_cast<const unsigned*>(p.agg[r] + (size_t)node * 64);
                #pragma unroll
                for (int k = 0; k < 32; ++k) {
                    unsigned u = arow[k >> 1];
                    float ak = __uint_as_float((k & 1) ? (u & 0xffff0000u) : (u << 16));
                    mm = fmaf(ak, w[r][k], mm);
                }
            } else {
                const float* arow = reinterpret_cast<const float*>(p.agg[r] + (size_t)node * 32);
                #pragma unroll
                for (int k = 0; k < 6; ++k)
                    mm = fmaf(arow[k], w[r][k], mm);
            }
        }
        const float* xrow = p.xdst + (size_t)node * D_IN;
        #pragma unroll
        for (int k = 0; k < D_IN; ++k)
            mm = fmaf(xrow[k], wr[k], mm);
        if (RES) mm += p.xdst[(size_t)node * 32 + dim];
        if (RELU) mm = fmaxf(mm, 0.f);
        if (li < 32) p.out[(size_t)node * 32 + dim] = mm;
    }
}

// ---------------- host ----------------

static inline char* alignp(char* p, size_t a) {
    return (char*)(((uintptr_t)p + a - 1) & ~(a - 1));
}

extern "C" void kernel_launch(void* const* d_in, const int* in_sizes, int n_in,
                              void* d_out, int out_size, void* d_ws, size_t ws_size,
                              hipStream_t stream)
{
    const float* x_stroke = (const float*)d_in[0];
    const float* x_brep   = (const float*)d_in[1];
    const int* ei0 = (const int*)d_in[2];
    const int* ei1 = (const int*)d_in[3];
    const int* ei2 = (const int*)d_in[4];
    const int* ei3 = (const int*)d_in[5];
    const int* ei4 = (const int*)d_in[6];
    const float* W0_rel  = (const float*)d_in[7];
    const float* b0_rel  = (const float*)d_in[8];
    const float* W0_root = (const float*)d_in[9];
    const float* Wb_rel  = (const float*)d_in[10];
    const float* bb_rel  = (const float*)d_in[11];
    const float* Wb_root = (const float*)d_in[12];
    float* out = (float*)d_out;

    // ---- workspace ----
    char* A = alignp((char*)d_ws, 256);
    int* edges_ch = (int*)A;                         // 5*EPAD ints (build; dead after csr)
    char* aggbase = A;                               // overlay: bf16/f32 agg rows after build
    int* boff = (int*)alignp((char*)(edges_ch + 5 * EPAD), 256);
    int* bcnt = (int*)alignp((char*)(boff + 5 * NBLKS * BOFF_STRIDE), 256);
    int* bbase = (int*)alignp((char*)(bcnt + 5 * NBKT_S), 256);
    float* xs = (float*)alignp((char*)(bbase + 5 * NBKT_S), 256);   // NS*32
    float* xb = (float*)alignp((char*)(xs + (size_t)NS * 32), 256); // NB*32
    int* edges_csr = (int*)alignp((char*)(xb + (size_t)NB * 32), 256);  // 5*EE
    int* rs_all = (int*)alignp((char*)(edges_csr + (size_t)5 * EE), 256);

    static const size_t AGGOFF[5] = {
        0,
        (size_t)NS * 64,
        (size_t)NS * 128,
        (size_t)NS * 128 + (size_t)NB * 64,
        (size_t)NS * 128 + (size_t)NB * 128
    };  // end = NS*192 + NB*128 = 25.6 MB <= 32.1 MB chunked-edge region

    // ---- build ----
    hipMemsetAsync(bcnt, 0, 5 * NBKT_S * sizeof(int), stream);
    bucket_sort_kernel<<<dim3(NBLKS, 5), 256, 0, stream>>>(ei0, ei1, ei2, ei3, ei4,
                                                           edges_ch, boff, bcnt);
    bscan_kernel<<<5, 1024, 0, stream>>>(bcnt, bbase);
    csr_build_kernel<<<dim3(NBKT_S, 5), 256, 0, stream>>>(edges_ch, boff, bbase,
                                                          edges_csr, rs_all);

    // ---- weight helpers ----
    auto relW = [&](int l, int r) -> const float* {
        return l == 0 ? W0_rel + r * 6 * 32 : Wb_rel + ((l - 1) * 5 + r) * 32 * 32;
    };
    auto relB = [&](int l, int r) -> const float* {
        return l == 0 ? b0_rel + r * 32 : bb_rel + ((l - 1) * 5 + r) * 32;
    };
    auto relWr = [&](int l, int r) -> const float* {
        return l == 0 ? W0_root + r * 6 * 32 : Wb_root + ((l - 1) * 5 + r) * 32 * 32;
    };

    const int AGGT[5] = {1, 0, 1, 2, 2};
    const int NDST[5] = {NS, NS, NB, NB, NS};

    auto mkAgg = [&](int l) -> AggArgs {
        AggArgs a;
        for (int r = 0; r < 5; ++r) {
            a.rs[r] = rs_all + r * (NS + 1);
            a.srcs[r] = edges_csr + (size_t)r * EE;
            a.agg[r] = aggbase + AGGOFF[r];
            a.ndst[r] = NDST[r];
            a.aggr[r] = AGGT[r];
            if (l == 0) a.xsrc[r] = (r == 3) ? x_brep : x_stroke;
            else        a.xsrc[r] = (r == 3) ? xb : xs;
        }
        return a;
    };
    auto mkMMs = [&](int l) -> MMArgs {   // stroke dst: rels 0,1,4
        MMArgs m;
        int rr[3] = {0, 1, 4};
        for (int i = 0; i < 3; ++i) {
            m.agg[i] = aggbase + AGGOFF[rr[i]];
            m.W[i] = relW(l, rr[i]); m.Wroot[i] = relWr(l, rr[i]); m.b[i] = relB(l, rr[i]);
        }
        m.xdst = (l == 0) ? x_stroke : xs;
        m.out = (l == 4) ? out : xs;
        m.ndst = NS;
        return m;
    };
    auto mkMMb = [&](int l) -> MMArgs {   // brep dst: rels 2,3
        MMArgs m;
        int rr[2] = {2, 3};
        for (int i = 0; i < 2; ++i) {
            m.agg[i] = aggbase + AGGOFF[rr[i]];
            m.W[i] = relW(l, rr[i]); m.Wroot[i] = relWr(l, rr[i]); m.b[i] = relB(l, rr[i]);
        }
        m.agg[2] = m.agg[0]; m.W[2] = m.W[0]; m.Wroot[2] = m.Wroot[0]; m.b[2] = m.b[0];
        m.xdst = (l == 0) ? x_brep : xb;
        m.out = (l == 4) ? out + (size_t)NS * 32 : xb;
        m.ndst = NB;
        return m;
    };

    const int GA = (NS + 31) / 32;            // 3125
    const int GMS = (NS + 63) / 64;           // 1563 blocks (4 waves x 16 nodes)
    const int GMB = (NB + 63) / 64;           // 782

    // layer 0 (D=6, no residual)
    agg_kernel<6><<<dim3(GA, 5), 256, 0, stream>>>(mkAgg(0));
    mm_kernel<6, 3, false, false><<<GMS, 256, 0, stream>>>(mkMMs(0));
    mm_kernel<6, 2, false, false><<<GMB, 256, 0, stream>>>(mkMMb(0));

    // layers 1..3 (D=32, residual, in-place)
    for (int l = 1; l <= 3; ++l) {
        agg_kernel<32><<<dim3(GA, 5), 256, 0, stream>>>(mkAgg(l));
        mm_kernel<32, 3, true, false><<<GMS, 256, 0, stream>>>(mkMMs(l));
        mm_kernel<32, 2, true, false><<<GMB, 256, 0, stream>>>(mkMMb(l));
    }

    // layer 4 (relu -> d_out)
    agg_kernel<32><<<dim3(GA, 5), 256, 0, stream>>>(mkAgg(4));
    mm_kernel<32, 3, true, true><<<GMS, 256, 0, stream>>>(mkMMs(4));
    mm_kernel<32, 2, true, true><<<GMB, 256, 0, stream>>>(mkMMb(4));

    (void)in_sizes; (void)n_in; (void)out_size; (void)ws_size;
}

// Round 8
// 1190.029 us; speedup vs baseline: 12.3644x; 1.1076x over previous
//
#include <hip/hip_runtime.h>
#include <math.h>

#define NS 100000
#define NB 50000
#define EE 1600000

#define BSH 8
#define BSZ 256                         // dst nodes per bucket
#define NBK_S ((NS + BSZ - 1) / BSZ)    // 391
#define NBK_B ((NB + BSZ - 1) / BSZ)    // 196
#define CHUNK 16384
#define NCH ((EE + CHUNK - 1) / CHUNK)  // 98

#define SRC_MASK 0x1FFFF
#define SSH 17

// ---------------- k1: per-chunk bucket histogram ----------------

__global__ __launch_bounds__(256) void hist_kernel(
    const int* __restrict__ e0, const int* __restrict__ e1, const int* __restrict__ e2,
    const int* __restrict__ e3, const int* __restrict__ e4, int* __restrict__ bcnt)
{
    int j = blockIdx.x, rel = blockIdx.y, tid = threadIdx.x;
    const int* ei = (rel == 0) ? e0 : (rel == 1) ? e1 : (rel == 2) ? e2 : (rel == 3) ? e3 : e4;
    int nb = (rel == 2 || rel == 3) ? NBK_B : NBK_S;
    __shared__ int hist[NBK_S];
    for (int i = tid; i < nb; i += 256) hist[i] = 0;
    __syncthreads();
    int es = j * CHUNK, ee2 = min(EE, es + CHUNK);
    for (int e = es + tid; e < ee2; e += 256)
        atomicAdd(&hist[ei[EE + e] >> BSH], 1);
    __syncthreads();
    for (int i = tid; i < nb; i += 256)
        if (hist[i]) atomicAdd(&bcnt[rel * NBK_S + i], hist[i]);
}

// ---------------- k2: per-relation bucket-base scan (+ cursor init) ----------------

__global__ __launch_bounds__(512) void bscan_kernel(const int* __restrict__ bcnt,
                                                    int* __restrict__ bbase,
                                                    int* __restrict__ gcur)
{
    int rel = blockIdx.x;
    int nb = (rel == 2 || rel == 3) ? NBK_B : NBK_S;
    __shared__ int s[512];
    int tid = threadIdx.x;
    int v = (tid < nb) ? bcnt[rel * NBK_S + tid] : 0;
    s[tid] = v;
    __syncthreads();
    for (int off = 1; off < 512; off <<= 1) {
        int t = (tid >= off) ? s[tid - off] : 0;
        __syncthreads();
        s[tid] += t;
        __syncthreads();
    }
    int ex = s[tid] - v;
    if (tid < nb) { bbase[rel * NBK_S + tid] = ex; gcur[rel * NBK_S + tid] = ex; }
}

// ---------------- k3: per-chunk LDS counting sort -> bucket-partitioned runs -------

__global__ __launch_bounds__(256, 2) void sort_kernel(
    const int* __restrict__ e0, const int* __restrict__ e1, const int* __restrict__ e2,
    const int* __restrict__ e3, const int* __restrict__ e4,
    int* __restrict__ ebkt, int* __restrict__ gcur)
{
    int j = blockIdx.x, rel = blockIdx.y, tid = threadIdx.x;
    const int* ei = (rel == 0) ? e0 : (rel == 1) ? e1 : (rel == 2) ? e2 : (rel == 3) ? e3 : e4;
    int nb = (rel == 2 || rel == 3) ? NBK_B : NBK_S;

    __shared__ int start[NBK_S + 1];
    __shared__ int cur[NBK_S];
    __shared__ int gbase[NBK_S];
    __shared__ int part[256];
    __shared__ int buf[CHUNK];

    int es = j * CHUNK, ee2 = min(EE, es + CHUNK);
    int n = ee2 - es;

    for (int i = tid; i < nb; i += 256) cur[i] = 0;     // cur = hist (temp)
    __syncthreads();
    for (int e = es + tid; e < ee2; e += 256)
        atomicAdd(&cur[ei[EE + e] >> BSH], 1);
    __syncthreads();

    // exclusive scan of cur[0..nb) -> start
    int v0 = (2 * tid < nb) ? cur[2 * tid] : 0;
    int v1 = (2 * tid + 1 < nb) ? cur[2 * tid + 1] : 0;
    part[tid] = v0 + v1;
    __syncthreads();
    for (int off = 1; off < 256; off <<= 1) {
        int t = (tid >= off) ? part[tid - off] : 0;
        __syncthreads();
        part[tid] += t;
        __syncthreads();
    }
    int run = (tid > 0) ? part[tid - 1] : 0;
    if (2 * tid < nb) start[2 * tid] = run;
    if (2 * tid + 1 < nb) start[2 * tid + 1] = run + v0;
    if (tid == 0) start[nb] = n;
    __syncthreads();
    for (int i = tid; i < nb; i += 256) cur[i] = start[i];  // cursors
    __syncthreads();

    // scatter chunk into bucket-sorted LDS buffer; reserve global runs
    for (int e = es + tid; e < ee2; e += 256) {
        int s = ei[e], d = ei[EE + e];
        int pos = atomicAdd(&cur[d >> BSH], 1);
        buf[pos] = ((d & (BSZ - 1)) << SSH) | s;
    }
    for (int b = tid; b < nb; b += 256) {
        int c = start[b + 1] - start[b];
        gbase[b] = c ? atomicAdd(&gcur[rel * NBK_S + b], c) : 0;
    }
    __syncthreads();

    // stream out: consecutive i -> consecutive positions within each run
    int* eo = ebkt + (size_t)rel * EE;
    for (int i = tid; i < n; i += 256) {
        int lo = 0, hi = nb;
        while (hi - lo > 1) { int mid = (lo + hi) >> 1; if (start[mid] <= i) lo = mid; else hi = mid; }
        eo[gbase[lo] + (i - start[lo])] = buf[i];
    }
}

// ---------------- k4: per-bucket CSR finalize (contiguous span, 256 slots) --------

__global__ __launch_bounds__(256, 8) void csr_kernel(
    const int* __restrict__ ebkt, const int* __restrict__ bcnt, const int* __restrict__ bbase,
    int* __restrict__ edges_csr, int* __restrict__ rs_all)
{
    int bkt = blockIdx.x, rel = blockIdx.y, tid = threadIdx.x;
    int nb = (rel == 2 || rel == 3) ? NBK_B : NBK_S;
    if (bkt >= nb) return;
    int nd = (rel == 2 || rel == 3) ? NB : NS;

    int base = bbase[rel * NBK_S + bkt];
    int cnt = bcnt[rel * NBK_S + bkt];
    const int* span = ebkt + (size_t)rel * EE + base;
    int* rs = rs_all + rel * (NS + 1);

    __shared__ int h[BSZ], s[BSZ], cu[BSZ];
    h[tid] = 0;
    __syncthreads();
    for (int i = tid; i < cnt; i += 256)
        atomicAdd(&h[span[i] >> SSH], 1);
    __syncthreads();
    s[tid] = h[tid];
    __syncthreads();
    for (int off = 1; off < 256; off <<= 1) {
        int t = (tid >= off) ? s[tid - off] : 0;
        __syncthreads();
        s[tid] += t;
        __syncthreads();
    }
    int exv = s[tid] - h[tid];
    cu[tid] = exv;
    int node = bkt * BSZ + tid;
    if (node < nd) rs[node] = base + exv;
    if (bkt == nb - 1 && tid == 0) rs[nd] = base + cnt;
    __syncthreads();

    int* outp = edges_csr + (size_t)rel * EE;
    for (int i = tid; i < cnt; i += 256) {
        int p = span[i];
        int pos = atomicAdd(&cu[p >> SSH], 1);
        outp[base + pos] = p & SRC_MASK;
    }
}

// ---------------- octet gathers (R6/R7 proven; full-wave shuffles) ----------------

template <int AGGR>
__device__ __forceinline__ float4 gath32(const float* __restrict__ xsrc,
                                         const int* __restrict__ srcs,
                                         int s0, int deg, int md, int li, int l8)
{
    float init = (AGGR == 2) ? -INFINITY : 0.f;
    float4 acc = {init, init, init, init};
    for (int bs = 0; bs < md; bs += 8) {
        int a = s0 + bs + l8;
        int idx = srcs[a < (EE - 1) ? a : (EE - 1)];
        #pragma unroll
        for (int jj = 0; jj < 8; ++jj) {
            int s = __shfl(idx, (li & ~7) + jj, 64);      // full-wave
            if (bs + jj < deg) {
                float4 v = *reinterpret_cast<const float4*>(xsrc + (size_t)s * 32 + l8 * 4);
                if (AGGR == 2) {
                    acc.x = fmaxf(acc.x, v.x); acc.y = fmaxf(acc.y, v.y);
                    acc.z = fmaxf(acc.z, v.z); acc.w = fmaxf(acc.w, v.w);
                } else {
                    acc.x += v.x; acc.y += v.y; acc.z += v.z; acc.w += v.w;
                }
            }
        }
    }
    return acc;
}

template <int AGGR>
__device__ __forceinline__ float gath6(const float* __restrict__ xsrc,
                                       const int* __restrict__ srcs,
                                       int s0, int deg, int md, int li, int l8)
{
    float acc = (AGGR == 2) ? -INFINITY : 0.f;
    for (int bs = 0; bs < md; bs += 8) {
        int a = s0 + bs + l8;
        int idx = srcs[a < (EE - 1) ? a : (EE - 1)];
        #pragma unroll
        for (int jj = 0; jj < 8; ++jj) {
            int s = __shfl(idx, (li & ~7) + jj, 64);      // full-wave
            if (bs + jj < deg && l8 < 6) {
                float v = xsrc[(size_t)s * 6 + l8];
                if (AGGR == 2) acc = fmaxf(acc, v); else acc += v;
            }
        }
    }
    return acc;
}

// ---------------- fused layer: gather -> LDS -> in-block matmul ----------------

struct FRel {
    const int* rs;
    const int* srcs;
    const float* xsrc;
    const float* W;
    const float* b;
    const float* Wroot;
};

template <int D, int AGGR>
__device__ __forceinline__ void do_gather(const FRel& R, int node, int nd,
                                          int li, int l8, int nl, float* aggRow)
{
    int nodec = min(node, nd - 1);
    int s0 = R.rs[nodec];
    int deg = R.rs[nodec + 1] - s0;
    if (node >= nd) deg = 0;
    int md = deg;
    md = max(md, __shfl_xor(md, 8, 64));
    md = max(md, __shfl_xor(md, 16, 64));
    md = max(md, __shfl_xor(md, 32, 64));
    if (D == 32) {
        float4 acc = gath32<AGGR>(R.xsrc, R.srcs, s0, deg, md, li, l8);
        if (AGGR == 1) { float inv = 1.f / (float)max(deg, 1); acc.x *= inv; acc.y *= inv; acc.z *= inv; acc.w *= inv; }
        if (AGGR == 2 && deg == 0) { acc.x = acc.y = acc.z = acc.w = 0.f; }
        *reinterpret_cast<float4*>(&aggRow[nl * 32 + l8 * 4]) = acc;
    } else {
        float acc = gath6<AGGR>(R.xsrc, R.srcs, s0, deg, md, li, l8);
        if (AGGR == 1) acc *= 1.f / (float)max(deg, 1);
        if (AGGR == 2 && deg == 0) acc = 0.f;
        aggRow[nl * 8 + l8] = (l8 < 6) ? acc : 0.f;
    }
}

template <int D, int NREL, bool RES, bool RELU, int A0, int A1, int A2>
__global__ __launch_bounds__(256, 4) void fused_kernel(
    FRel r0, FRel r1, FRel r2,
    const float* xdst, float* __restrict__ outp, int nd)
{
    constexpr int DP = (D == 32) ? 32 : 8;
    __shared__ float sW[NREL][D * 32];
    __shared__ float sWr[D * 32];
    __shared__ float aggL[NREL][32 * DP];
    __shared__ float xL[32 * DP];

    int tid = threadIdx.x, li = tid & 63, l8 = tid & 7, nl = tid >> 3;
    int node = blockIdx.x * 32 + nl;

    for (int i = tid; i < D * 32; i += 256) {
        sW[0][i] = r0.W[i];
        if (NREL > 1) sW[1][i] = r1.W[i];
        if (NREL > 2) sW[2][i] = r2.W[i];
        float wv = r0.Wroot[i];
        if (NREL > 1) wv += r1.Wroot[i];
        if (NREL > 2) wv += r2.Wroot[i];
        sWr[i] = wv;
    }

    bool valid = node < nd;
    if (D == 32) {
        float4 xv = {0.f, 0.f, 0.f, 0.f};
        if (valid) xv = *reinterpret_cast<const float4*>(xdst + (size_t)node * 32 + l8 * 4);
        *reinterpret_cast<float4*>(&xL[nl * 32 + l8 * 4]) = xv;
    } else {
        float xv = (valid && l8 < 6) ? xdst[(size_t)node * 6 + l8] : 0.f;
        xL[nl * 8 + l8] = xv;
    }

    do_gather<D, A0>(r0, node, nd, li, l8, nl, aggL[0]);
    if (NREL > 1) do_gather<D, A1>(r1, node, nd, li, l8, nl, aggL[1]);
    if (NREL > 2) do_gather<D, A2>(r2, node, nd, li, l8, nl, aggL[2]);

    __syncthreads();

    int dim = tid & 31, grp = tid >> 5;
    #pragma unroll
    for (int it = 0; it < 4; ++it) {
        int n2 = grp + it * 8;
        int gnode = blockIdx.x * 32 + n2;
        if (gnode < nd) {
            float mm = r0.b[dim];
            if (NREL > 1) mm += r1.b[dim];
            if (NREL > 2) mm += r2.b[dim];
            #pragma unroll
            for (int r = 0; r < NREL; ++r)
                #pragma unroll
                for (int k = 0; k < D; ++k)
                    mm = fmaf(aggL[r][n2 * DP + k], sW[r][k * 32 + dim], mm);
            #pragma unroll
            for (int k = 0; k < D; ++k)
                mm = fmaf(xL[n2 * DP + k], sWr[k * 32 + dim], mm);
            if (RES) mm += xL[n2 * DP + dim];
            if (RELU) mm = fmaxf(mm, 0.f);
            outp[(size_t)gnode * 32 + dim] = mm;
        }
    }
}

// ---------------- host ----------------

static inline char* alignp(char* p, size_t a) {
    return (char*)(((uintptr_t)p + a - 1) & ~(a - 1));
}

extern "C" void kernel_launch(void* const* d_in, const int* in_sizes, int n_in,
                              void* d_out, int out_size, void* d_ws, size_t ws_size,
                              hipStream_t stream)
{
    const float* x_stroke = (const float*)d_in[0];
    const float* x_brep   = (const float*)d_in[1];
    const int* ei0 = (const int*)d_in[2];
    const int* ei1 = (const int*)d_in[3];
    const int* ei2 = (const int*)d_in[4];
    const int* ei3 = (const int*)d_in[5];
    const int* ei4 = (const int*)d_in[6];
    const float* W0_rel  = (const float*)d_in[7];
    const float* b0_rel  = (const float*)d_in[8];
    const float* W0_root = (const float*)d_in[9];
    const float* Wb_rel  = (const float*)d_in[10];
    const float* bb_rel  = (const float*)d_in[11];
    const float* Wb_root = (const float*)d_in[12];
    float* out = (float*)d_out;

    // ---- workspace ----
    char* A = alignp((char*)d_ws, 256);
    int* ebkt = (int*)A;                                 // 5*EE ints (dead after csr_kernel)
    float* xs0 = (float*)A;                              // overlay: L0/L2 outputs
    float* xb0 = xs0 + (size_t)NS * 32;
    char* Aend = (char*)(ebkt + (size_t)5 * EE);         // 32MB > 19.2MB feats
    float* xs1 = (float*)alignp(Aend, 256);
    float* xb1 = xs1 + (size_t)NS * 32;
    int* edges_csr = (int*)alignp((char*)(xb1 + (size_t)NB * 32), 256);  // 5*EE
    int* rs_all = (int*)alignp((char*)(edges_csr + (size_t)5 * EE), 256); // 5*(NS+1)
    int* bcnt  = (int*)alignp((char*)(rs_all + 5 * (NS + 1)), 256);       // 5*NBK_S
    int* bbase = (int*)alignp((char*)(bcnt + 5 * NBK_S), 256);
    int* gcur  = (int*)alignp((char*)(bbase + 5 * NBK_S), 256);

    // ---- build ----
    hipMemsetAsync(bcnt, 0, 5 * NBK_S * sizeof(int), stream);
    hist_kernel<<<dim3(NCH, 5), 256, 0, stream>>>(ei0, ei1, ei2, ei3, ei4, bcnt);
    bscan_kernel<<<5, 512, 0, stream>>>(bcnt, bbase, gcur);
    sort_kernel<<<dim3(NCH, 5), 256, 0, stream>>>(ei0, ei1, ei2, ei3, ei4, ebkt, gcur);
    csr_kernel<<<dim3(NBK_S, 5), 256, 0, stream>>>(ebkt, bcnt, bbase, edges_csr, rs_all);

    // ---- weights ----
    auto relW = [&](int l, int r) -> const float* {
        return l == 0 ? W0_rel + r * 6 * 32 : Wb_rel + ((l - 1) * 5 + r) * 32 * 32;
    };
    auto relB = [&](int l, int r) -> const float* {
        return l == 0 ? b0_rel + r * 32 : bb_rel + ((l - 1) * 5 + r) * 32;
    };
    auto relWr = [&](int l, int r) -> const float* {
        return l == 0 ? W0_root + r * 6 * 32 : Wb_root + ((l - 1) * 5 + r) * 32 * 32;
    };
    auto FR = [&](int l, int r, const float* xsrc) -> FRel {
        FRel R;
        R.rs = rs_all + r * (NS + 1);
        R.srcs = edges_csr + (size_t)r * EE;
        R.xsrc = xsrc;
        R.W = relW(l, r); R.b = relB(l, r); R.Wroot = relWr(l, r);
        return R;
    };

    const int GS = (NS + 31) / 32;   // 3125
    const int GB = (NB + 31) / 32;   // 1563

    // layer 0 (D=6, no residual) -> xs0/xb0 (overlay region; build is done)
    fused_kernel<6, 3, false, false, 1, 0, 2><<<GS, 256, 0, stream>>>(
        FR(0, 0, x_stroke), FR(0, 1, x_stroke), FR(0, 4, x_stroke), x_stroke, xs0, NS);
    fused_kernel<6, 2, false, false, 1, 2, 0><<<GB, 256, 0, stream>>>(
        FR(0, 2, x_stroke), FR(0, 3, x_brep), FR(0, 2, x_stroke), x_brep, xb0, NB);

    // layers 1..4 (D=32, residual; ping-pong; layer 4 relu -> d_out)
    const float* cs = xs0; const float* cb = xb0;
    for (int l = 1; l <= 4; ++l) {
        float* os = (l == 4) ? out : ((l & 1) ? xs1 : xs0);
        float* ob = (l == 4) ? out + (size_t)NS * 32 : ((l & 1) ? xb1 : xb0);
        FRel s0 = FR(l, 0, cs), s1 = FR(l, 1, cs), s2 = FR(l, 4, cs);
        FRel b0 = FR(l, 2, cs), b1 = FR(l, 3, cb);
        if (l < 4) {
            fused_kernel<32, 3, true, false, 1, 0, 2><<<GS, 256, 0, stream>>>(s0, s1, s2, cs, os, NS);
            fused_kernel<32, 2, true, false, 1, 2, 0><<<GB, 256, 0, stream>>>(b0, b1, b0, cb, ob, NB);
        } else {
            fused_kernel<32, 3, true, true, 1, 0, 2><<<GS, 256, 0, stream>>>(s0, s1, s2, cs, os, NS);
            fused_kernel<32, 2, true, true, 1, 2, 0><<<GB, 256, 0, stream>>>(b0, b1, b0, cb, ob, NB);
        }
        cs = os; cb = ob;
    }
    (void)in_sizes; (void)n_in; (void)out_size; (void)ws_size;
}

// Round 9
// 985.912 us; speedup vs baseline: 14.9243x; 1.2070x over previous
//
#include <hip/hip_runtime.h>
#include <math.h>

#define NS 100000
#define NB 50000
#define EE 1600000

#define BSH 8
#define BSZ 256                         // dst nodes per bucket
#define NBK_S ((NS + BSZ - 1) / BSZ)    // 391
#define NBK_B ((NB + BSZ - 1) / BSZ)    // 196
#define CHUNK 16384
#define NCH ((EE + CHUNK - 1) / CHUNK)  // 98

#define SRC_MASK 0x1FFFF
#define SSH 17

typedef unsigned int u32;
typedef unsigned short u16;

// ---------------- k1: per-chunk bucket histogram ----------------

__global__ __launch_bounds__(256) void hist_kernel(
    const int* __restrict__ e0, const int* __restrict__ e1, const int* __restrict__ e2,
    const int* __restrict__ e3, const int* __restrict__ e4, int* __restrict__ bcnt)
{
    int j = blockIdx.x, rel = blockIdx.y, tid = threadIdx.x;
    const int* ei = (rel == 0) ? e0 : (rel == 1) ? e1 : (rel == 2) ? e2 : (rel == 3) ? e3 : e4;
    int nb = (rel == 2 || rel == 3) ? NBK_B : NBK_S;
    __shared__ int hist[NBK_S];
    for (int i = tid; i < nb; i += 256) hist[i] = 0;
    __syncthreads();
    int es = j * CHUNK, ee2 = min(EE, es + CHUNK);
    for (int e = es + tid; e < ee2; e += 256)
        atomicAdd(&hist[ei[EE + e] >> BSH], 1);
    __syncthreads();
    for (int i = tid; i < nb; i += 256)
        if (hist[i]) atomicAdd(&bcnt[rel * NBK_S + i], hist[i]);
}

// ---------------- k2: per-relation bucket-base scan (+ cursor init) ----------------

__global__ __launch_bounds__(512) void bscan_kernel(const int* __restrict__ bcnt,
                                                    int* __restrict__ bbase,
                                                    int* __restrict__ gcur)
{
    int rel = blockIdx.x;
    int nb = (rel == 2 || rel == 3) ? NBK_B : NBK_S;
    __shared__ int s[512];
    int tid = threadIdx.x;
    int v = (tid < nb) ? bcnt[rel * NBK_S + tid] : 0;
    s[tid] = v;
    __syncthreads();
    for (int off = 1; off < 512; off <<= 1) {
        int t = (tid >= off) ? s[tid - off] : 0;
        __syncthreads();
        s[tid] += t;
        __syncthreads();
    }
    int ex = s[tid] - v;
    if (tid < nb) { bbase[rel * NBK_S + tid] = ex; gcur[rel * NBK_S + tid] = ex; }
}

// ---------------- k3: per-chunk LDS counting sort -> bucket-partitioned runs -------

__global__ __launch_bounds__(256, 2) void sort_kernel(
    const int* __restrict__ e0, const int* __restrict__ e1, const int* __restrict__ e2,
    const int* __restrict__ e3, const int* __restrict__ e4,
    int* __restrict__ ebkt, int* __restrict__ gcur)
{
    int j = blockIdx.x, rel = blockIdx.y, tid = threadIdx.x;
    const int* ei = (rel == 0) ? e0 : (rel == 1) ? e1 : (rel == 2) ? e2 : (rel == 3) ? e3 : e4;
    int nb = (rel == 2 || rel == 3) ? NBK_B : NBK_S;

    __shared__ int start[NBK_S + 1];
    __shared__ int cur[NBK_S];
    __shared__ int gbase[NBK_S];
    __shared__ int part[256];
    __shared__ int buf[CHUNK];

    int es = j * CHUNK, ee2 = min(EE, es + CHUNK);
    int n = ee2 - es;

    for (int i = tid; i < nb; i += 256) cur[i] = 0;     // cur = hist (temp)
    __syncthreads();
    for (int e = es + tid; e < ee2; e += 256)
        atomicAdd(&cur[ei[EE + e] >> BSH], 1);
    __syncthreads();

    int v0 = (2 * tid < nb) ? cur[2 * tid] : 0;
    int v1 = (2 * tid + 1 < nb) ? cur[2 * tid + 1] : 0;
    part[tid] = v0 + v1;
    __syncthreads();
    for (int off = 1; off < 256; off <<= 1) {
        int t = (tid >= off) ? part[tid - off] : 0;
        __syncthreads();
        part[tid] += t;
        __syncthreads();
    }
    int run = (tid > 0) ? part[tid - 1] : 0;
    if (2 * tid < nb) start[2 * tid] = run;
    if (2 * tid + 1 < nb) start[2 * tid + 1] = run + v0;
    if (tid == 0) start[nb] = n;
    __syncthreads();
    for (int i = tid; i < nb; i += 256) cur[i] = start[i];  // cursors
    __syncthreads();

    for (int e = es + tid; e < ee2; e += 256) {
        int s = ei[e], d = ei[EE + e];
        int pos = atomicAdd(&cur[d >> BSH], 1);
        buf[pos] = ((d & (BSZ - 1)) << SSH) | s;
    }
    for (int b = tid; b < nb; b += 256) {
        int c = start[b + 1] - start[b];
        gbase[b] = c ? atomicAdd(&gcur[rel * NBK_S + b], c) : 0;
    }
    __syncthreads();

    int* eo = ebkt + (size_t)rel * EE;
    for (int i = tid; i < n; i += 256) {
        int lo = 0, hi = nb;
        while (hi - lo > 1) { int mid = (lo + hi) >> 1; if (start[mid] <= i) lo = mid; else hi = mid; }
        eo[gbase[lo] + (i - start[lo])] = buf[i];
    }
}

// ---------------- k4: per-bucket CSR finalize (contiguous span, 256 slots) --------

__global__ __launch_bounds__(256, 8) void csr_kernel(
    const int* __restrict__ ebkt, const int* __restrict__ bcnt, const int* __restrict__ bbase,
    int* __restrict__ edges_csr, int* __restrict__ rs_all)
{
    int bkt = blockIdx.x, rel = blockIdx.y, tid = threadIdx.x;
    int nb = (rel == 2 || rel == 3) ? NBK_B : NBK_S;
    if (bkt >= nb) return;
    int nd = (rel == 2 || rel == 3) ? NB : NS;

    int base = bbase[rel * NBK_S + bkt];
    int cnt = bcnt[rel * NBK_S + bkt];
    const int* span = ebkt + (size_t)rel * EE + base;
    int* rs = rs_all + rel * (NS + 1);

    __shared__ int h[BSZ], s[BSZ], cu[BSZ];
    h[tid] = 0;
    __syncthreads();
    for (int i = tid; i < cnt; i += 256)
        atomicAdd(&h[span[i] >> SSH], 1);
    __syncthreads();
    s[tid] = h[tid];
    __syncthreads();
    for (int off = 1; off < 256; off <<= 1) {
        int t = (tid >= off) ? s[tid - off] : 0;
        __syncthreads();
        s[tid] += t;
        __syncthreads();
    }
    int exv = s[tid] - h[tid];
    cu[tid] = exv;
    int node = bkt * BSZ + tid;
    if (node < nd) rs[node] = base + exv;
    if (bkt == nb - 1 && tid == 0) rs[nd] = base + cnt;
    __syncthreads();

    int* outp = edges_csr + (size_t)rel * EE;
    for (int i = tid; i < cnt; i += 256) {
        int p = span[i];
        int pos = atomicAdd(&cu[p >> SSH], 1);
        outp[base + pos] = p & SRC_MASK;
    }
}

// ---------------- bf16 helpers ----------------

__device__ __forceinline__ u32 bfpack(float a, float b) {
    u32 ua = __float_as_uint(a), ub = __float_as_uint(b);
    ua = (ua + 0x7fffu + ((ua >> 16) & 1u)) >> 16;
    ub = (ub + 0x7fffu + ((ub >> 16) & 1u)) >> 16;
    return ua | (ub << 16);
}
__device__ __forceinline__ u16 bf1(float f) {
    u32 u = __float_as_uint(f);
    return (u16)((u + 0x7fffu + ((u >> 16) & 1u)) >> 16);
}
__device__ __forceinline__ float bflo(u32 u) { return __uint_as_float(u << 16); }
__device__ __forceinline__ float bfhi(u32 u) { return __uint_as_float(u & 0xffff0000u); }

// ---------------- octet gathers (full-wave shuffles; R5 lesson) ----------------

template <int AGGR>
__device__ __forceinline__ float4 gath32bf(const u32* __restrict__ xsrc,
                                           const int* __restrict__ srcs,
                                           int s0, int deg, int md, int li, int l8)
{
    float init = (AGGR == 2) ? -INFINITY : 0.f;
    float4 acc = {init, init, init, init};
    for (int bs = 0; bs < md; bs += 8) {
        int a = s0 + bs + l8;
        int idx = srcs[a < (EE - 1) ? a : (EE - 1)];
        #pragma unroll
        for (int jj = 0; jj < 8; ++jj) {
            int s = __shfl(idx, (li & ~7) + jj, 64);      // full-wave
            if (bs + jj < deg) {
                uint2 v = *reinterpret_cast<const uint2*>(xsrc + (size_t)s * 16 + l8 * 2);
                float f0 = bflo(v.x), f1 = bfhi(v.x), f2 = bflo(v.y), f3 = bfhi(v.y);
                if (AGGR == 2) {
                    acc.x = fmaxf(acc.x, f0); acc.y = fmaxf(acc.y, f1);
                    acc.z = fmaxf(acc.z, f2); acc.w = fmaxf(acc.w, f3);
                } else {
                    acc.x += f0; acc.y += f1; acc.z += f2; acc.w += f3;
                }
            }
        }
    }
    return acc;
}

template <int AGGR>
__device__ __forceinline__ float gath6(const float* __restrict__ xsrc,
                                       const int* __restrict__ srcs,
                                       int s0, int deg, int md, int li, int l8)
{
    float acc = (AGGR == 2) ? -INFINITY : 0.f;
    for (int bs = 0; bs < md; bs += 8) {
        int a = s0 + bs + l8;
        int idx = srcs[a < (EE - 1) ? a : (EE - 1)];
        #pragma unroll
        for (int jj = 0; jj < 8; ++jj) {
            int s = __shfl(idx, (li & ~7) + jj, 64);      // full-wave
            if (bs + jj < deg && l8 < 6) {
                float v = xsrc[(size_t)s * 6 + l8];
                if (AGGR == 2) acc = fmaxf(acc, v); else acc += v;
            }
        }
    }
    return acc;
}

// ---------------- fused layer ----------------

struct FRel {
    const int* rs;
    const int* srcs;
    const void* xsrc;
    const float* W;
    const float* b;
    const float* Wroot;
};

template <int D, int AGGR>
__device__ __forceinline__ void do_gather(const FRel& R, int node, int nd,
                                          int li, int l8, int nl,
                                          u32* aggP, float* aggF)
{
    int nodec = min(node, nd - 1);
    int s0 = R.rs[nodec];
    int deg = R.rs[nodec + 1] - s0;
    if (node >= nd) deg = 0;
    int md = deg;
    md = max(md, __shfl_xor(md, 8, 64));
    md = max(md, __shfl_xor(md, 16, 64));
    md = max(md, __shfl_xor(md, 32, 64));
    if (D == 32) {
        float4 acc = gath32bf<AGGR>((const u32*)R.xsrc, R.srcs, s0, deg, md, li, l8);
        if (AGGR == 1) { float inv = 1.f / (float)max(deg, 1); acc.x *= inv; acc.y *= inv; acc.z *= inv; acc.w *= inv; }
        if (AGGR == 2 && deg == 0) { acc.x = acc.y = acc.z = acc.w = 0.f; }
        aggP[nl * 16 + l8 * 2]     = bfpack(acc.x, acc.y);
        aggP[nl * 16 + l8 * 2 + 1] = bfpack(acc.z, acc.w);
    } else {
        float acc = gath6<AGGR>((const float*)R.xsrc, R.srcs, s0, deg, md, li, l8);
        if (AGGR == 1) acc *= 1.f / (float)max(deg, 1);
        if (AGGR == 2 && deg == 0) acc = 0.f;
        aggF[nl * 8 + l8] = (l8 < 6) ? acc : 0.f;
    }
}

template <int D, int NREL, bool RES, bool RELU, bool OUTBF, int A0, int A1, int A2>
__global__ __launch_bounds__(256, 6) void fused_kernel(
    FRel r0, FRel r1, FRel r2,
    const void* xdst, void* outp, int nd)
{
    __shared__ float sW[NREL][D * 32];
    __shared__ float sWr[D * 32];
    // D==32: packed bf16 pairs; D==6: f32
    __shared__ u32 aggP[(D == 32) ? NREL * 32 * 16 : 1];
    __shared__ float aggF[(D == 32) ? 1 : NREL * 32 * 8];
    __shared__ u32 xP[(D == 32) ? 32 * 16 : 1];
    __shared__ float xF[(D == 32) ? 1 : 32 * 8];

    int tid = threadIdx.x, li = tid & 63, l8 = tid & 7, nl = tid >> 3;
    int node = blockIdx.x * 32 + nl;
    bool valid = node < nd;

    for (int i = tid; i < D * 32; i += 256) {
        sW[0][i] = r0.W[i];
        if (NREL > 1) sW[1][i] = r1.W[i];
        if (NREL > 2) sW[2][i] = r2.W[i];
        float wv = r0.Wroot[i];
        if (NREL > 1) wv += r1.Wroot[i];
        if (NREL > 2) wv += r2.Wroot[i];
        sWr[i] = wv;
    }

    if (D == 32) {
        uint2 xv = {0u, 0u};
        if (valid) xv = *reinterpret_cast<const uint2*>((const u32*)xdst + (size_t)node * 16 + l8 * 2);
        xP[nl * 16 + l8 * 2] = xv.x;
        xP[nl * 16 + l8 * 2 + 1] = xv.y;
    } else {
        float xv = (valid && l8 < 6) ? ((const float*)xdst)[(size_t)node * 6 + l8] : 0.f;
        xF[nl * 8 + l8] = xv;
    }

    do_gather<D, A0>(r0, node, nd, li, l8, nl, aggP + 0 * 32 * 16, aggF + 0 * 32 * 8);
    if (NREL > 1) do_gather<D, A1>(r1, node, nd, li, l8, nl, aggP + 1 * 32 * 16, aggF + 1 * 32 * 8);
    if (NREL > 2) do_gather<D, A2>(r2, node, nd, li, l8, nl, aggP + 2 * 32 * 16, aggF + 2 * 32 * 8);

    __syncthreads();

    int dim = tid & 31, grp = tid >> 5;
    #pragma unroll
    for (int it = 0; it < 4; ++it) {
        int n2 = grp + it * 8;
        int gnode = blockIdx.x * 32 + n2;
        if (gnode < nd) {
            float mm = r0.b[dim];
            if (NREL > 1) mm += r1.b[dim];
            if (NREL > 2) mm += r2.b[dim];
            if (D == 32) {
                #pragma unroll
                for (int r = 0; r < NREL; ++r) {
                    const u32* ar = aggP + r * 32 * 16 + n2 * 16;
                    #pragma unroll
                    for (int k2 = 0; k2 < 16; ++k2) {
                        u32 u = ar[k2];
                        mm = fmaf(bflo(u), sW[r][(2 * k2) * 32 + dim], mm);
                        mm = fmaf(bfhi(u), sW[r][(2 * k2 + 1) * 32 + dim], mm);
                    }
                }
                const u32* xr = xP + n2 * 16;
                #pragma unroll
                for (int k2 = 0; k2 < 16; ++k2) {
                    u32 u = xr[k2];
                    mm = fmaf(bflo(u), sWr[(2 * k2) * 32 + dim], mm);
                    mm = fmaf(bfhi(u), sWr[(2 * k2 + 1) * 32 + dim], mm);
                }
                if (RES) {
                    u32 u = xr[dim >> 1];
                    mm += (dim & 1) ? bfhi(u) : bflo(u);
                }
            } else {
                #pragma unroll
                for (int r = 0; r < NREL; ++r)
                    #pragma unroll
                    for (int k = 0; k < 6; ++k)
                        mm = fmaf(aggF[r * 32 * 8 + n2 * 8 + k], sW[r][k * 32 + dim], mm);
                #pragma unroll
                for (int k = 0; k < 6; ++k)
                    mm = fmaf(xF[n2 * 8 + k], sWr[k * 32 + dim], mm);
            }
            if (RELU) mm = fmaxf(mm, 0.f);
            if (OUTBF) ((u16*)outp)[(size_t)gnode * 32 + dim] = bf1(mm);
            else       ((float*)outp)[(size_t)gnode * 32 + dim] = mm;
        }
    }
}

// ---------------- host ----------------

static inline char* alignp(char* p, size_t a) {
    return (char*)(((uintptr_t)p + a - 1) & ~(a - 1));
}

extern "C" void kernel_launch(void* const* d_in, const int* in_sizes, int n_in,
                              void* d_out, int out_size, void* d_ws, size_t ws_size,
                              hipStream_t stream)
{
    const float* x_stroke = (const float*)d_in[0];
    const float* x_brep   = (const float*)d_in[1];
    const int* ei0 = (const int*)d_in[2];
    const int* ei1 = (const int*)d_in[3];
    const int* ei2 = (const int*)d_in[4];
    const int* ei3 = (const int*)d_in[5];
    const int* ei4 = (const int*)d_in[6];
    const float* W0_rel  = (const float*)d_in[7];
    const float* b0_rel  = (const float*)d_in[8];
    const float* W0_root = (const float*)d_in[9];
    const float* Wb_rel  = (const float*)d_in[10];
    const float* bb_rel  = (const float*)d_in[11];
    const float* Wb_root = (const float*)d_in[12];
    float* out = (float*)d_out;

    // ---- workspace ----
    char* A = alignp((char*)d_ws, 256);
    int* ebkt = (int*)A;                                 // 5*EE ints (dead after csr_kernel)
    u32* xs0 = (u32*)A;                                  // overlay: bf16 feats (16 u32/node)
    u32* xb0 = xs0 + (size_t)NS * 16;
    char* Aend = (char*)(ebkt + (size_t)5 * EE);
    u32* xs1 = (u32*)alignp(Aend, 256);
    u32* xb1 = xs1 + (size_t)NS * 16;
    int* edges_csr = (int*)alignp((char*)(xb1 + (size_t)NB * 16), 256);   // 5*EE
    int* rs_all = (int*)alignp((char*)(edges_csr + (size_t)5 * EE), 256); // 5*(NS+1)
    int* bcnt  = (int*)alignp((char*)(rs_all + 5 * (NS + 1)), 256);
    int* bbase = (int*)alignp((char*)(bcnt + 5 * NBK_S), 256);
    int* gcur  = (int*)alignp((char*)(bbase + 5 * NBK_S), 256);

    // ---- build ----
    hipMemsetAsync(bcnt, 0, 5 * NBK_S * sizeof(int), stream);
    hist_kernel<<<dim3(NCH, 5), 256, 0, stream>>>(ei0, ei1, ei2, ei3, ei4, bcnt);
    bscan_kernel<<<5, 512, 0, stream>>>(bcnt, bbase, gcur);
    sort_kernel<<<dim3(NCH, 5), 256, 0, stream>>>(ei0, ei1, ei2, ei3, ei4, ebkt, gcur);
    csr_kernel<<<dim3(NBK_S, 5), 256, 0, stream>>>(ebkt, bcnt, bbase, edges_csr, rs_all);

    // ---- weights ----
    auto relW = [&](int l, int r) -> const float* {
        return l == 0 ? W0_rel + r * 6 * 32 : Wb_rel + ((l - 1) * 5 + r) * 32 * 32;
    };
    auto relB = [&](int l, int r) -> const float* {
        return l == 0 ? b0_rel + r * 32 : bb_rel + ((l - 1) * 5 + r) * 32;
    };
    auto relWr = [&](int l, int r) -> const float* {
        return l == 0 ? W0_root + r * 6 * 32 : Wb_root + ((l - 1) * 5 + r) * 32 * 32;
    };
    auto FR = [&](int l, int r, const void* xsrc) -> FRel {
        FRel R;
        R.rs = rs_all + r * (NS + 1);
        R.srcs = edges_csr + (size_t)r * EE;
        R.xsrc = xsrc;
        R.W = relW(l, r); R.b = relB(l, r); R.Wroot = relWr(l, r);
        return R;
    };

    const int GS = (NS + 31) / 32;   // 3125
    const int GB = (NB + 31) / 32;   // 1563

    // layer 0 (D=6 f32 inputs, no residual) -> bf16 xs0/xb0
    fused_kernel<6, 3, false, false, true, 1, 0, 2><<<GS, 256, 0, stream>>>(
        FR(0, 0, x_stroke), FR(0, 1, x_stroke), FR(0, 4, x_stroke), x_stroke, xs0, NS);
    fused_kernel<6, 2, false, false, true, 1, 2, 0><<<GB, 256, 0, stream>>>(
        FR(0, 2, x_stroke), FR(0, 3, x_brep), FR(0, 2, x_stroke), x_brep, xb0, NB);

    // layers 1..3 (D=32 bf16, residual, ping-pong); layer 4 relu -> f32 d_out
    const u32* cs = xs0; const u32* cb = xb0;
    for (int l = 1; l <= 3; ++l) {
        u32* os = (l & 1) ? xs1 : xs0;
        u32* ob = (l & 1) ? xb1 : xb0;
        fused_kernel<32, 3, true, false, true, 1, 0, 2><<<GS, 256, 0, stream>>>(
            FR(l, 0, cs), FR(l, 1, cs), FR(l, 4, cs), cs, os, NS);
        fused_kernel<32, 2, true, false, true, 1, 2, 0><<<GB, 256, 0, stream>>>(
            FR(l, 2, cs), FR(l, 3, cb), FR(l, 2, cs), cb, ob, NB);
        cs = os; cb = ob;
    }
    fused_kernel<32, 3, true, true, false, 1, 0, 2><<<GS, 256, 0, stream>>>(
        FR(4, 0, cs), FR(4, 1, cs), FR(4, 4, cs), cs, out, NS);
    fused_kernel<32, 2, true, true, false, 1, 2, 0><<<GB, 256, 0, stream>>>(
        FR(4, 2, cs), FR(4, 3, cb), FR(4, 2, cs), cb, out + (size_t)NS * 32, NB);

    (void)in_sizes; (void)n_in; (void)out_size; (void)ws_size;
}

// Round 10
// 843.102 us; speedup vs baseline: 17.4523x; 1.1694x over previous
//
#include <hip/hip_runtime.h>
#include <math.h>

#define NS 100000
#define NB 50000
#define EE 1600000

#define BSH 8
#define BSZ 256                         // dst nodes per bucket
#define NBK_S ((NS + BSZ - 1) / BSZ)    // 391
#define NBK_B ((NB + BSZ - 1) / BSZ)    // 196
#define CHUNK 16384
#define NCH ((EE + CHUNK - 1) / CHUNK)  // 98

#define SRC_MASK 0x1FFFF
#define SSH 17

typedef unsigned int u32;
typedef unsigned short u16;

// ---------------- k1: per-chunk bucket histogram ----------------

__global__ __launch_bounds__(256) void hist_kernel(
    const int* __restrict__ e0, const int* __restrict__ e1, const int* __restrict__ e2,
    const int* __restrict__ e3, const int* __restrict__ e4, int* __restrict__ bcnt)
{
    int j = blockIdx.x, rel = blockIdx.y, tid = threadIdx.x;
    const int* ei = (rel == 0) ? e0 : (rel == 1) ? e1 : (rel == 2) ? e2 : (rel == 3) ? e3 : e4;
    int nb = (rel == 2 || rel == 3) ? NBK_B : NBK_S;
    __shared__ int hist[NBK_S];
    for (int i = tid; i < nb; i += 256) hist[i] = 0;
    __syncthreads();
    int es = j * CHUNK, ee2 = min(EE, es + CHUNK);
    for (int e = es + tid; e < ee2; e += 256)
        atomicAdd(&hist[ei[EE + e] >> BSH], 1);
    __syncthreads();
    for (int i = tid; i < nb; i += 256)
        if (hist[i]) atomicAdd(&bcnt[rel * NBK_S + i], hist[i]);
}

// ---------------- k2: per-relation bucket-base scan (+ cursor init) ----------------

__global__ __launch_bounds__(512) void bscan_kernel(const int* __restrict__ bcnt,
                                                    int* __restrict__ bbase,
                                                    int* __restrict__ gcur)
{
    int rel = blockIdx.x;
    int nb = (rel == 2 || rel == 3) ? NBK_B : NBK_S;
    __shared__ int s[512];
    int tid = threadIdx.x;
    int v = (tid < nb) ? bcnt[rel * NBK_S + tid] : 0;
    s[tid] = v;
    __syncthreads();
    for (int off = 1; off < 512; off <<= 1) {
        int t = (tid >= off) ? s[tid - off] : 0;
        __syncthreads();
        s[tid] += t;
        __syncthreads();
    }
    int ex = s[tid] - v;
    if (tid < nb) { bbase[rel * NBK_S + tid] = ex; gcur[rel * NBK_S + tid] = ex; }
}

// ---------------- k3: per-chunk LDS counting sort -> bucket-partitioned runs -------

__global__ __launch_bounds__(256, 2) void sort_kernel(
    const int* __restrict__ e0, const int* __restrict__ e1, const int* __restrict__ e2,
    const int* __restrict__ e3, const int* __restrict__ e4,
    int* __restrict__ ebkt, int* __restrict__ gcur)
{
    int j = blockIdx.x, rel = blockIdx.y, tid = threadIdx.x;
    const int* ei = (rel == 0) ? e0 : (rel == 1) ? e1 : (rel == 2) ? e2 : (rel == 3) ? e3 : e4;
    int nb = (rel == 2 || rel == 3) ? NBK_B : NBK_S;

    __shared__ int start[NBK_S + 1];
    __shared__ int cur[NBK_S];
    __shared__ int gbase[NBK_S];
    __shared__ int part[256];
    __shared__ int buf[CHUNK];

    int es = j * CHUNK, ee2 = min(EE, es + CHUNK);
    int n = ee2 - es;

    for (int i = tid; i < nb; i += 256) cur[i] = 0;     // cur = hist (temp)
    __syncthreads();
    for (int e = es + tid; e < ee2; e += 256)
        atomicAdd(&cur[ei[EE + e] >> BSH], 1);
    __syncthreads();

    int v0 = (2 * tid < nb) ? cur[2 * tid] : 0;
    int v1 = (2 * tid + 1 < nb) ? cur[2 * tid + 1] : 0;
    part[tid] = v0 + v1;
    __syncthreads();
    for (int off = 1; off < 256; off <<= 1) {
        int t = (tid >= off) ? part[tid - off] : 0;
        __syncthreads();
        part[tid] += t;
        __syncthreads();
    }
    int run = (tid > 0) ? part[tid - 1] : 0;
    if (2 * tid < nb) start[2 * tid] = run;
    if (2 * tid + 1 < nb) start[2 * tid + 1] = run + v0;
    if (tid == 0) start[nb] = n;
    __syncthreads();
    for (int i = tid; i < nb; i += 256) cur[i] = start[i];  // cursors
    __syncthreads();

    for (int e = es + tid; e < ee2; e += 256) {
        int s = ei[e], d = ei[EE + e];
        int pos = atomicAdd(&cur[d >> BSH], 1);
        buf[pos] = ((d & (BSZ - 1)) << SSH) | s;
    }
    for (int b = tid; b < nb; b += 256) {
        int c = start[b + 1] - start[b];
        gbase[b] = c ? atomicAdd(&gcur[rel * NBK_S + b], c) : 0;
    }
    __syncthreads();

    int* eo = ebkt + (size_t)rel * EE;
    for (int i = tid; i < n; i += 256) {
        int lo = 0, hi = nb;
        while (hi - lo > 1) { int mid = (lo + hi) >> 1; if (start[mid] <= i) lo = mid; else hi = mid; }
        eo[gbase[lo] + (i - start[lo])] = buf[i];
    }
}

// ---------------- k4: per-bucket CSR finalize (contiguous span, 256 slots) --------

__global__ __launch_bounds__(256, 8) void csr_kernel(
    const int* __restrict__ ebkt, const int* __restrict__ bcnt, const int* __restrict__ bbase,
    int* __restrict__ edges_csr, int* __restrict__ rs_all)
{
    int bkt = blockIdx.x, rel = blockIdx.y, tid = threadIdx.x;
    int nb = (rel == 2 || rel == 3) ? NBK_B : NBK_S;
    if (bkt >= nb) return;
    int nd = (rel == 2 || rel == 3) ? NB : NS;

    int base = bbase[rel * NBK_S + bkt];
    int cnt = bcnt[rel * NBK_S + bkt];
    const int* span = ebkt + (size_t)rel * EE + base;
    int* rs = rs_all + rel * (NS + 1);

    __shared__ int h[BSZ], s[BSZ], cu[BSZ];
    h[tid] = 0;
    __syncthreads();
    for (int i = tid; i < cnt; i += 256)
        atomicAdd(&h[span[i] >> SSH], 1);
    __syncthreads();
    s[tid] = h[tid];
    __syncthreads();
    for (int off = 1; off < 256; off <<= 1) {
        int t = (tid >= off) ? s[tid - off] : 0;
        __syncthreads();
        s[tid] += t;
        __syncthreads();
    }
    int exv = s[tid] - h[tid];
    cu[tid] = exv;
    int node = bkt * BSZ + tid;
    if (node < nd) rs[node] = base + exv;
    if (bkt == nb - 1 && tid == 0) rs[nd] = base + cnt;
    __syncthreads();

    int* outp = edges_csr + (size_t)rel * EE;
    for (int i = tid; i < cnt; i += 256) {
        int p = span[i];
        int pos = atomicAdd(&cu[p >> SSH], 1);
        outp[base + pos] = p & SRC_MASK;
    }
}

// ---------------- bf16 helpers ----------------

__device__ __forceinline__ u32 bfpack(float a, float b) {
    u32 ua = __float_as_uint(a), ub = __float_as_uint(b);
    ua = (ua + 0x7fffu + ((ua >> 16) & 1u)) >> 16;
    ub = (ub + 0x7fffu + ((ub >> 16) & 1u)) >> 16;
    return ua | (ub << 16);
}
__device__ __forceinline__ u16 bf1(float f) {
    u32 u = __float_as_uint(f);
    return (u16)((u + 0x7fffu + ((u >> 16) & 1u)) >> 16);
}
__device__ __forceinline__ float bflo(u32 u) { return __uint_as_float(u << 16); }
__device__ __forceinline__ float bfhi(u32 u) { return __uint_as_float(u & 0xffff0000u); }

// ---------------- octet gathers (full-wave shuffles; R5 lesson) ----------------

template <int AGGR>
__device__ __forceinline__ float4 gath32bf(const u32* __restrict__ xsrc,
                                           const int* __restrict__ srcs,
                                           int s0, int deg, int md, int li, int l8)
{
    float init = (AGGR == 2) ? -INFINITY : 0.f;
    float4 acc = {init, init, init, init};
    for (int bs = 0; bs < md; bs += 8) {
        int a = s0 + bs + l8;
        int idx = srcs[a < (EE - 1) ? a : (EE - 1)];
        #pragma unroll
        for (int jj = 0; jj < 8; ++jj) {
            int s = __shfl(idx, (li & ~7) + jj, 64);      // full-wave
            if (bs + jj < deg) {
                uint2 v = *reinterpret_cast<const uint2*>(xsrc + (size_t)s * 16 + l8 * 2);
                float f0 = bflo(v.x), f1 = bfhi(v.x), f2 = bflo(v.y), f3 = bfhi(v.y);
                if (AGGR == 2) {
                    acc.x = fmaxf(acc.x, f0); acc.y = fmaxf(acc.y, f1);
                    acc.z = fmaxf(acc.z, f2); acc.w = fmaxf(acc.w, f3);
                } else {
                    acc.x += f0; acc.y += f1; acc.z += f2; acc.w += f3;
                }
            }
        }
    }
    return acc;
}

template <int AGGR>
__device__ __forceinline__ float gath6(const float* __restrict__ xsrc,
                                       const int* __restrict__ srcs,
                                       int s0, int deg, int md, int li, int l8)
{
    float acc = (AGGR == 2) ? -INFINITY : 0.f;
    for (int bs = 0; bs < md; bs += 8) {
        int a = s0 + bs + l8;
        int idx = srcs[a < (EE - 1) ? a : (EE - 1)];
        #pragma unroll
        for (int jj = 0; jj < 8; ++jj) {
            int s = __shfl(idx, (li & ~7) + jj, 64);      // full-wave
            if (bs + jj < deg && l8 < 6) {
                float v = xsrc[(size_t)s * 6 + l8];
                if (AGGR == 2) acc = fmaxf(acc, v); else acc += v;
            }
        }
    }
    return acc;
}

// ---------------- fused layer ----------------

struct FRel {
    const int* rs;
    const int* srcs;
    const void* xsrc;
    const float* W;
    const float* b;
    const float* Wroot;
};

template <int D, int AGGR>
__device__ __forceinline__ void do_gather(const FRel& R, int node, int nd,
                                          int li, int l8, int nl,
                                          u32* aggP, float* aggF)
{
    int nodec = min(node, nd - 1);
    int s0 = R.rs[nodec];
    int deg = R.rs[nodec + 1] - s0;
    if (node >= nd) deg = 0;
    int md = deg;
    md = max(md, __shfl_xor(md, 8, 64));
    md = max(md, __shfl_xor(md, 16, 64));
    md = max(md, __shfl_xor(md, 32, 64));
    if (D == 32) {
        float4 acc = gath32bf<AGGR>((const u32*)R.xsrc, R.srcs, s0, deg, md, li, l8);
        if (AGGR == 1) { float inv = 1.f / (float)max(deg, 1); acc.x *= inv; acc.y *= inv; acc.z *= inv; acc.w *= inv; }
        if (AGGR == 2 && deg == 0) { acc.x = acc.y = acc.z = acc.w = 0.f; }
        aggP[nl * 16 + l8 * 2]     = bfpack(acc.x, acc.y);
        aggP[nl * 16 + l8 * 2 + 1] = bfpack(acc.z, acc.w);
    } else {
        float acc = gath6<AGGR>((const float*)R.xsrc, R.srcs, s0, deg, md, li, l8);
        if (AGGR == 1) acc *= 1.f / (float)max(deg, 1);
        if (AGGR == 2 && deg == 0) acc = 0.f;
        aggF[nl * 8 + l8] = (l8 < 6) ? acc : 0.f;
    }
}

template <int D, int NREL, bool RES, bool RELU, bool OUTBF, int A0, int A1, int A2>
__global__ __launch_bounds__(256, 8) void fused_kernel(
    FRel r0, FRel r1, FRel r2,
    const void* xdst, void* outp, int nd)
{
    // D==32: weights in packed bf16 (LDS diet -> 8 blocks/CU); D==6: f32
    __shared__ u32 sWb[(D == 32) ? NREL * 16 * 32 : 1];
    __shared__ float sW6[(D == 32) ? 1 : NREL * 6 * 32];
    __shared__ float sWr[D * 32];
    __shared__ u32 aggP[(D == 32) ? NREL * 32 * 16 : 1];
    __shared__ float aggF[(D == 32) ? 1 : NREL * 32 * 8];
    __shared__ u32 xP[(D == 32) ? 32 * 16 : 1];
    __shared__ float xF[(D == 32) ? 1 : 32 * 8];

    int tid = threadIdx.x, li = tid & 63, l8 = tid & 7, nl = tid >> 3;
    int node = blockIdx.x * 32 + nl;
    bool valid = node < nd;

    if (D == 32) {
        // pack W[2k2][dim], W[2k2+1][dim] into one u32 at [r][k2*32+dim]
        for (int i = tid; i < 16 * 32; i += 256) {
            int k2 = i >> 5, dim = i & 31;
            sWb[0 * 512 + i] = bfpack(r0.W[(2 * k2) * 32 + dim], r0.W[(2 * k2 + 1) * 32 + dim]);
            if (NREL > 1) sWb[1 * 512 + i] = bfpack(r1.W[(2 * k2) * 32 + dim], r1.W[(2 * k2 + 1) * 32 + dim]);
            if (NREL > 2) sWb[2 * 512 + i] = bfpack(r2.W[(2 * k2) * 32 + dim], r2.W[(2 * k2 + 1) * 32 + dim]);
        }
    } else {
        for (int i = tid; i < 6 * 32; i += 256) {
            sW6[0 * 192 + i] = r0.W[i];
            if (NREL > 1) sW6[1 * 192 + i] = r1.W[i];
            if (NREL > 2) sW6[2 * 192 + i] = r2.W[i];
        }
    }
    for (int i = tid; i < D * 32; i += 256) {
        float wv = r0.Wroot[i];
        if (NREL > 1) wv += r1.Wroot[i];
        if (NREL > 2) wv += r2.Wroot[i];
        sWr[i] = wv;
    }

    if (D == 32) {
        uint2 xv = {0u, 0u};
        if (valid) xv = *reinterpret_cast<const uint2*>((const u32*)xdst + (size_t)node * 16 + l8 * 2);
        xP[nl * 16 + l8 * 2] = xv.x;
        xP[nl * 16 + l8 * 2 + 1] = xv.y;
    } else {
        float xv = (valid && l8 < 6) ? ((const float*)xdst)[(size_t)node * 6 + l8] : 0.f;
        xF[nl * 8 + l8] = xv;
    }

    do_gather<D, A0>(r0, node, nd, li, l8, nl, aggP + 0 * 32 * 16, aggF + 0 * 32 * 8);
    if (NREL > 1) do_gather<D, A1>(r1, node, nd, li, l8, nl, aggP + 1 * 32 * 16, aggF + 1 * 32 * 8);
    if (NREL > 2) do_gather<D, A2>(r2, node, nd, li, l8, nl, aggP + 2 * 32 * 16, aggF + 2 * 32 * 8);

    __syncthreads();

    int dim = tid & 31, grp = tid >> 5;
    #pragma unroll
    for (int it = 0; it < 4; ++it) {
        int n2 = grp + it * 8;
        int gnode = blockIdx.x * 32 + n2;
        if (gnode < nd) {
            float mm = r0.b[dim];
            if (NREL > 1) mm += r1.b[dim];
            if (NREL > 2) mm += r2.b[dim];
            if (D == 32) {
                #pragma unroll
                for (int r = 0; r < NREL; ++r) {
                    const u32* ar = aggP + r * 32 * 16 + n2 * 16;
                    const u32* wr = sWb + r * 512;
                    #pragma unroll
                    for (int k2 = 0; k2 < 16; ++k2) {
                        u32 a = ar[k2];
                        u32 w = wr[k2 * 32 + dim];
                        mm = fmaf(bflo(a), bflo(w), mm);
                        mm = fmaf(bfhi(a), bfhi(w), mm);
                    }
                }
                const u32* xr = xP + n2 * 16;
                #pragma unroll
                for (int k2 = 0; k2 < 16; ++k2) {
                    u32 u = xr[k2];
                    mm = fmaf(bflo(u), sWr[(2 * k2) * 32 + dim], mm);
                    mm = fmaf(bfhi(u), sWr[(2 * k2 + 1) * 32 + dim], mm);
                }
                if (RES) {
                    u32 u = xr[dim >> 1];
                    mm += (dim & 1) ? bfhi(u) : bflo(u);
                }
            } else {
                #pragma unroll
                for (int r = 0; r < NREL; ++r)
                    #pragma unroll
                    for (int k = 0; k < 6; ++k)
                        mm = fmaf(aggF[r * 32 * 8 + n2 * 8 + k], sW6[r * 192 + k * 32 + dim], mm);
                #pragma unroll
                for (int k = 0; k < 6; ++k)
                    mm = fmaf(xF[n2 * 8 + k], sWr[k * 32 + dim], mm);
            }
            if (RELU) mm = fmaxf(mm, 0.f);
            if (OUTBF) ((u16*)outp)[(size_t)gnode * 32 + dim] = bf1(mm);
            else       ((float*)outp)[(size_t)gnode * 32 + dim] = mm;
        }
    }
}

// ---------------- host ----------------

static inline char* alignp(char* p, size_t a) {
    return (char*)(((uintptr_t)p + a - 1) & ~(a - 1));
}

extern "C" void kernel_launch(void* const* d_in, const int* in_sizes, int n_in,
                              void* d_out, int out_size, void* d_ws, size_t ws_size,
                              hipStream_t stream)
{
    const float* x_stroke = (const float*)d_in[0];
    const float* x_brep   = (const float*)d_in[1];
    const int* ei0 = (const int*)d_in[2];
    const int* ei1 = (const int*)d_in[3];
    const int* ei2 = (const int*)d_in[4];
    const int* ei3 = (const int*)d_in[5];
    const int* ei4 = (const int*)d_in[6];
    const float* W0_rel  = (const float*)d_in[7];
    const float* b0_rel  = (const float*)d_in[8];
    const float* W0_root = (const float*)d_in[9];
    const float* Wb_rel  = (const float*)d_in[10];
    const float* bb_rel  = (const float*)d_in[11];
    const float* Wb_root = (const float*)d_in[12];
    float* out = (float*)d_out;

    // ---- workspace ----
    char* A = alignp((char*)d_ws, 256);
    int* ebkt = (int*)A;                                 // 5*EE ints (dead after csr_kernel)
    u32* xs0 = (u32*)A;                                  // overlay: bf16 feats (16 u32/node)
    u32* xb0 = xs0 + (size_t)NS * 16;
    char* Aend = (char*)(ebkt + (size_t)5 * EE);
    u32* xs1 = (u32*)alignp(Aend, 256);
    u32* xb1 = xs1 + (size_t)NS * 16;
    int* edges_csr = (int*)alignp((char*)(xb1 + (size_t)NB * 16), 256);   // 5*EE
    int* rs_all = (int*)alignp((char*)(edges_csr + (size_t)5 * EE), 256); // 5*(NS+1)
    int* bcnt  = (int*)alignp((char*)(rs_all + 5 * (NS + 1)), 256);
    int* bbase = (int*)alignp((char*)(bcnt + 5 * NBK_S), 256);
    int* gcur  = (int*)alignp((char*)(bbase + 5 * NBK_S), 256);

    // ---- build ----
    hipMemsetAsync(bcnt, 0, 5 * NBK_S * sizeof(int), stream);
    hist_kernel<<<dim3(NCH, 5), 256, 0, stream>>>(ei0, ei1, ei2, ei3, ei4, bcnt);
    bscan_kernel<<<5, 512, 0, stream>>>(bcnt, bbase, gcur);
    sort_kernel<<<dim3(NCH, 5), 256, 0, stream>>>(ei0, ei1, ei2, ei3, ei4, ebkt, gcur);
    csr_kernel<<<dim3(NBK_S, 5), 256, 0, stream>>>(ebkt, bcnt, bbase, edges_csr, rs_all);

    // ---- weights ----
    auto relW = [&](int l, int r) -> const float* {
        return l == 0 ? W0_rel + r * 6 * 32 : Wb_rel + ((l - 1) * 5 + r) * 32 * 32;
    };
    auto relB = [&](int l, int r) -> const float* {
        return l == 0 ? b0_rel + r * 32 : bb_rel + ((l - 1) * 5 + r) * 32;
    };
    auto relWr = [&](int l, int r) -> const float* {
        return l == 0 ? W0_root + r * 6 * 32 : Wb_root + ((l - 1) * 5 + r) * 32 * 32;
    };
    auto FR = [&](int l, int r, const void* xsrc) -> FRel {
        FRel R;
        R.rs = rs_all + r * (NS + 1);
        R.srcs = edges_csr + (size_t)r * EE;
        R.xsrc = xsrc;
        R.W = relW(l, r); R.b = relB(l, r); R.Wroot = relWr(l, r);
        return R;
    };

    const int GS = (NS + 31) / 32;   // 3125
    const int GB = (NB + 31) / 32;   // 1563

    // layer 0 (D=6 f32 inputs, no residual) -> bf16 xs0/xb0
    fused_kernel<6, 3, false, false, true, 1, 0, 2><<<GS, 256, 0, stream>>>(
        FR(0, 0, x_stroke), FR(0, 1, x_stroke), FR(0, 4, x_stroke), x_stroke, xs0, NS);
    fused_kernel<6, 2, false, false, true, 1, 2, 0><<<GB, 256, 0, stream>>>(
        FR(0, 2, x_stroke), FR(0, 3, x_brep), FR(0, 2, x_stroke), x_brep, xb0, NB);

    // layers 1..3 (D=32 bf16, residual, ping-pong); layer 4 relu -> f32 d_out
    const u32* cs = xs0; const u32* cb = xb0;
    for (int l = 1; l <= 3; ++l) {
        u32* os = (l & 1) ? xs1 : xs0;
        u32* ob = (l & 1) ? xb1 : xb0;
        fused_kernel<32, 3, true, false, true, 1, 0, 2><<<GS, 256, 0, stream>>>(
            FR(l, 0, cs), FR(l, 1, cs), FR(l, 4, cs), cs, os, NS);
        fused_kernel<32, 2, true, false, true, 1, 2, 0><<<GB, 256, 0, stream>>>(
            FR(l, 2, cs), FR(l, 3, cb), FR(l, 2, cs), cb, ob, NB);
        cs = os; cb = ob;
    }
    fused_kernel<32, 3, true, true, false, 1, 0, 2><<<GS, 256, 0, stream>>>(
        FR(4, 0, cs), FR(4, 1, cs), FR(4, 4, cs), cs, out, NS);
    fused_kernel<32, 2, true, true, false, 1, 2, 0><<<GB, 256, 0, stream>>>(
        FR(4, 2, cs), FR(4, 3, cb), FR(4, 2, cs), cb, out + (size_t)NS * 32, NB);

    (void)in_sizes; (void)n_in; (void)out_size; (void)ws_size;
}

// Round 11
// 711.580 us; speedup vs baseline: 20.6780x; 1.1848x over previous
//
#include <hip/hip_runtime.h>
#include <math.h>

#define NS 100000
#define NB 50000
#define EE 1600000

#define BSH 8
#define BSZ 256                         // dst nodes per bucket
#define NBK_S ((NS + BSZ - 1) / BSZ)    // 391
#define NBK_B ((NB + BSZ - 1) / BSZ)    // 196
#define CHUNK 16384                     // hist chunking
#define NCH ((EE + CHUNK - 1) / CHUNK)  // 98
#define SCH 8192                        // sort chunking (LDS diet)
#define NSC ((EE + SCH - 1) / SCH)      // 196

#define SRC_MASK 0x1FFFF
#define SSH 17

typedef unsigned int u32;
typedef unsigned short u16;

// ---------------- k1: per-chunk bucket histogram ----------------

__global__ __launch_bounds__(256) void hist_kernel(
    const int* __restrict__ e0, const int* __restrict__ e1, const int* __restrict__ e2,
    const int* __restrict__ e3, const int* __restrict__ e4, int* __restrict__ bcnt)
{
    int j = blockIdx.x, rel = blockIdx.y, tid = threadIdx.x;
    const int* ei = (rel == 0) ? e0 : (rel == 1) ? e1 : (rel == 2) ? e2 : (rel == 3) ? e3 : e4;
    int nb = (rel == 2 || rel == 3) ? NBK_B : NBK_S;
    __shared__ int hist[NBK_S];
    for (int i = tid; i < nb; i += 256) hist[i] = 0;
    __syncthreads();
    int es = j * CHUNK, ee2 = min(EE, es + CHUNK);
    for (int e = es + tid; e < ee2; e += 256)
        atomicAdd(&hist[ei[EE + e] >> BSH], 1);
    __syncthreads();
    for (int i = tid; i < nb; i += 256)
        if (hist[i]) atomicAdd(&bcnt[rel * NBK_S + i], hist[i]);
}

// ---------------- k2: per-relation bucket-base scan (+ cursor init) ----------------

__global__ __launch_bounds__(512) void bscan_kernel(const int* __restrict__ bcnt,
                                                    int* __restrict__ bbase,
                                                    int* __restrict__ gcur)
{
    int rel = blockIdx.x;
    int nb = (rel == 2 || rel == 3) ? NBK_B : NBK_S;
    __shared__ int s[512];
    int tid = threadIdx.x;
    int v = (tid < nb) ? bcnt[rel * NBK_S + tid] : 0;
    s[tid] = v;
    __syncthreads();
    for (int off = 1; off < 512; off <<= 1) {
        int t = (tid >= off) ? s[tid - off] : 0;
        __syncthreads();
        s[tid] += t;
        __syncthreads();
    }
    int ex = s[tid] - v;
    if (tid < nb) { bbase[rel * NBK_S + tid] = ex; gcur[rel * NBK_S + tid] = ex; }
}

// ---------------- k3: per-chunk LDS counting sort -> bucket-partitioned runs -------
// 8K chunks (38.5 KB LDS -> 4 blocks/CU); stream-out = per-wave bucket-run copy.

__global__ __launch_bounds__(256, 4) void sort_kernel(
    const int* __restrict__ e0, const int* __restrict__ e1, const int* __restrict__ e2,
    const int* __restrict__ e3, const int* __restrict__ e4,
    int* __restrict__ ebkt, int* __restrict__ gcur)
{
    int j = blockIdx.x, rel = blockIdx.y, tid = threadIdx.x;
    const int* ei = (rel == 0) ? e0 : (rel == 1) ? e1 : (rel == 2) ? e2 : (rel == 3) ? e3 : e4;
    int nb = (rel == 2 || rel == 3) ? NBK_B : NBK_S;

    __shared__ int start[NBK_S + 1];
    __shared__ int cur[NBK_S];
    __shared__ int gbase[NBK_S];
    __shared__ int part[256];
    __shared__ int buf[SCH];

    int es = j * SCH, ee2 = min(EE, es + SCH);
    int n = ee2 - es;

    for (int i = tid; i < nb; i += 256) cur[i] = 0;     // cur = hist (temp)
    __syncthreads();
    for (int e = es + tid; e < ee2; e += 256)
        atomicAdd(&cur[ei[EE + e] >> BSH], 1);
    __syncthreads();

    int v0 = (2 * tid < nb) ? cur[2 * tid] : 0;
    int v1 = (2 * tid + 1 < nb) ? cur[2 * tid + 1] : 0;
    part[tid] = v0 + v1;
    __syncthreads();
    for (int off = 1; off < 256; off <<= 1) {
        int t = (tid >= off) ? part[tid - off] : 0;
        __syncthreads();
        part[tid] += t;
        __syncthreads();
    }
    int run = (tid > 0) ? part[tid - 1] : 0;
    if (2 * tid < nb) start[2 * tid] = run;
    if (2 * tid + 1 < nb) start[2 * tid + 1] = run + v0;
    if (tid == 0) start[nb] = n;
    __syncthreads();
    for (int i = tid; i < nb; i += 256) cur[i] = start[i];  // cursors
    __syncthreads();

    for (int e = es + tid; e < ee2; e += 256) {
        int s = ei[e], d = ei[EE + e];
        int pos = atomicAdd(&cur[d >> BSH], 1);
        buf[pos] = ((d & (BSZ - 1)) << SSH) | s;
    }
    for (int b = tid; b < nb; b += 256) {
        int c = start[b + 1] - start[b];
        gbase[b] = c ? atomicAdd(&gcur[rel * NBK_S + b], c) : 0;
    }
    __syncthreads();

    // stream out: wave w copies runs of buckets w, w+4, ... (no search)
    int* eo = ebkt + (size_t)rel * EE;
    int w = tid >> 6, l = tid & 63;
    for (int b = w; b < nb; b += 4) {
        int sb = start[b], c = start[b + 1] - sb, gb = gbase[b];
        for (int i = l; i < c; i += 64)
            eo[gb + i] = buf[sb + i];
    }
}

// ---------------- k4: per-bucket CSR finalize (contiguous span, 256 slots) --------

__global__ __launch_bounds__(256, 8) void csr_kernel(
    const int* __restrict__ ebkt, const int* __restrict__ bcnt, const int* __restrict__ bbase,
    int* __restrict__ edges_csr, int* __restrict__ rs_all)
{
    int bkt = blockIdx.x, rel = blockIdx.y, tid = threadIdx.x;
    int nb = (rel == 2 || rel == 3) ? NBK_B : NBK_S;
    if (bkt >= nb) return;
    int nd = (rel == 2 || rel == 3) ? NB : NS;

    int base = bbase[rel * NBK_S + bkt];
    int cnt = bcnt[rel * NBK_S + bkt];
    const int* span = ebkt + (size_t)rel * EE + base;
    int* rs = rs_all + rel * (NS + 1);

    __shared__ int h[BSZ], s[BSZ], cu[BSZ];
    h[tid] = 0;
    __syncthreads();
    for (int i = tid; i < cnt; i += 256)
        atomicAdd(&h[span[i] >> SSH], 1);
    __syncthreads();
    s[tid] = h[tid];
    __syncthreads();
    for (int off = 1; off < 256; off <<= 1) {
        int t = (tid >= off) ? s[tid - off] : 0;
        __syncthreads();
        s[tid] += t;
        __syncthreads();
    }
    int exv = s[tid] - h[tid];
    cu[tid] = exv;
    int node = bkt * BSZ + tid;
    if (node < nd) rs[node] = base + exv;
    if (bkt == nb - 1 && tid == 0) rs[nd] = base + cnt;
    __syncthreads();

    int* outp = edges_csr + (size_t)rel * EE;
    for (int i = tid; i < cnt; i += 256) {
        int p = span[i];
        int pos = atomicAdd(&cu[p >> SSH], 1);
        outp[base + pos] = p & SRC_MASK;
    }
}

// ---------------- bf16 helpers ----------------

__device__ __forceinline__ u32 bfpack(float a, float b) {
    u32 ua = __float_as_uint(a), ub = __float_as_uint(b);
    ua = (ua + 0x7fffu + ((ua >> 16) & 1u)) >> 16;
    ub = (ub + 0x7fffu + ((ub >> 16) & 1u)) >> 16;
    return ua | (ub << 16);
}
__device__ __forceinline__ u16 bf1(float f) {
    u32 u = __float_as_uint(f);
    return (u16)((u + 0x7fffu + ((u >> 16) & 1u)) >> 16);
}
__device__ __forceinline__ float bflo(u32 u) { return __uint_as_float(u << 16); }
__device__ __forceinline__ float bfhi(u32 u) { return __uint_as_float(u & 0xffff0000u); }

// ---------------- gathers ----------------
// D=32: 16-edge rounds, 16B loads. Octet = 2 groups x 4 lanes; group g handles
// edges of parity g, lane q=(l8&3) covers row bytes [q*16, q*16+16) = 8 bf16 dims.
// Loop bound is per-octet (deg is octet-uniform: all 8 lanes share the node), so
// intra-octet shuffles always source lanes that are active (R5 hazard avoided).

template <int AGGR>
__device__ __forceinline__ void gath32bf(const u32* __restrict__ xsrc,
                                         const int* __restrict__ srcs,
                                         int s0, int deg, int li, int l8,
                                         float (&acc)[8])
{
    float init = (AGGR == 2) ? -INFINITY : 0.f;
    #pragma unroll
    for (int d = 0; d < 8; ++d) acc[d] = init;
    int grp = l8 >> 2, q = l8 & 3;
    int lim = s0 + deg - 1;
    int obase = li & ~7;
    for (int bs = 0; bs < deg; bs += 16) {
        int a0 = s0 + bs + 2 * l8;
        int ix0 = srcs[a0 < lim ? a0 : lim];
        int ix1 = srcs[a0 + 1 < lim ? a0 + 1 : lim];
        #pragma unroll
        for (int sub = 0; sub < 8; ++sub) {
            int sa = __shfl(ix0, obase + sub, 64);
            int sb = __shfl(ix1, obase + sub, 64);
            int s = grp ? sb : sa;
            int e = bs + 2 * sub + grp;
            if (e < deg) {
                uint4 v = *reinterpret_cast<const uint4*>(xsrc + (size_t)s * 16 + q * 4);
                float f0 = bflo(v.x), f1 = bfhi(v.x), f2 = bflo(v.y), f3 = bfhi(v.y);
                float f4 = bflo(v.z), f5 = bfhi(v.z), f6 = bflo(v.w), f7 = bfhi(v.w);
                if (AGGR == 2) {
                    acc[0] = fmaxf(acc[0], f0); acc[1] = fmaxf(acc[1], f1);
                    acc[2] = fmaxf(acc[2], f2); acc[3] = fmaxf(acc[3], f3);
                    acc[4] = fmaxf(acc[4], f4); acc[5] = fmaxf(acc[5], f5);
                    acc[6] = fmaxf(acc[6], f6); acc[7] = fmaxf(acc[7], f7);
                } else {
                    acc[0] += f0; acc[1] += f1; acc[2] += f2; acc[3] += f3;
                    acc[4] += f4; acc[5] += f5; acc[6] += f6; acc[7] += f7;
                }
            }
        }
    }
    // combine the two edge-parity groups (lanes l8 and l8^4, same q)
    #pragma unroll
    for (int d = 0; d < 8; ++d) {
        float o = __shfl_xor(acc[d], 4, 64);
        acc[d] = (AGGR == 2) ? fmaxf(acc[d], o) : (acc[d] + o);
    }
}

template <int AGGR>
__device__ __forceinline__ float gath6(const float* __restrict__ xsrc,
                                       const int* __restrict__ srcs,
                                       int s0, int deg, int md, int li, int l8)
{
    float acc = (AGGR == 2) ? -INFINITY : 0.f;
    for (int bs = 0; bs < md; bs += 8) {
        int a = s0 + bs + l8;
        int idx = srcs[a < (EE - 1) ? a : (EE - 1)];
        #pragma unroll
        for (int jj = 0; jj < 8; ++jj) {
            int s = __shfl(idx, (li & ~7) + jj, 64);      // full-wave
            if (bs + jj < deg && l8 < 6) {
                float v = xsrc[(size_t)s * 6 + l8];
                if (AGGR == 2) acc = fmaxf(acc, v); else acc += v;
            }
        }
    }
    return acc;
}

// ---------------- fused layer ----------------

struct FRel {
    const int* rs;
    const int* srcs;
    const void* xsrc;
    const float* W;
    const float* b;
    const float* Wroot;
};

template <int D, int AGGR>
__device__ __forceinline__ void do_gather(const FRel& R, int node, int nd,
                                          int li, int l8, int nl,
                                          u32* aggP, float* aggF)
{
    int nodec = min(node, nd - 1);
    int s0 = R.rs[nodec];
    int deg = R.rs[nodec + 1] - s0;
    if (node >= nd) deg = 0;
    if (D == 32) {
        float acc[8];
        gath32bf<AGGR>((const u32*)R.xsrc, R.srcs, s0, deg, li, l8, acc);
        if (AGGR == 1) {
            float inv = 1.f / (float)max(deg, 1);
            #pragma unroll
            for (int d = 0; d < 8; ++d) acc[d] *= inv;
        }
        if (AGGR == 2 && deg == 0) {
            #pragma unroll
            for (int d = 0; d < 8; ++d) acc[d] = 0.f;
        }
        int grp = l8 >> 2, q = l8 & 3;
        uint2 o;
        if (grp == 0) { o.x = bfpack(acc[0], acc[1]); o.y = bfpack(acc[2], acc[3]); }
        else          { o.x = bfpack(acc[4], acc[5]); o.y = bfpack(acc[6], acc[7]); }
        *reinterpret_cast<uint2*>(aggP + nl * 16 + q * 4 + grp * 2) = o;
    } else {
        int md = deg;
        md = max(md, __shfl_xor(md, 8, 64));
        md = max(md, __shfl_xor(md, 16, 64));
        md = max(md, __shfl_xor(md, 32, 64));
        float acc = gath6<AGGR>((const float*)R.xsrc, R.srcs, s0, deg, md, li, l8);
        if (AGGR == 1) acc *= 1.f / (float)max(deg, 1);
        if (AGGR == 2 && deg == 0) acc = 0.f;
        aggF[nl * 8 + l8] = (l8 < 6) ? acc : 0.f;
    }
}

template <int D, int NREL, bool RES, bool RELU, bool OUTBF, int A0, int A1, int A2>
__global__ __launch_bounds__(256, 8) void fused_kernel(
    FRel r0, FRel r1, FRel r2,
    const void* xdst, void* outp, int nd)
{
    // D==32: weights in packed bf16 (LDS diet -> 8 blocks/CU); D==6: f32
    __shared__ u32 sWb[(D == 32) ? NREL * 16 * 32 : 1];
    __shared__ float sW6[(D == 32) ? 1 : NREL * 6 * 32];
    __shared__ float sWr[D * 32];
    __shared__ u32 aggP[(D == 32) ? NREL * 32 * 16 : 1];
    __shared__ float aggF[(D == 32) ? 1 : NREL * 32 * 8];
    __shared__ u32 xP[(D == 32) ? 32 * 16 : 1];
    __shared__ float xF[(D == 32) ? 1 : 32 * 8];

    int tid = threadIdx.x, li = tid & 63, l8 = tid & 7, nl = tid >> 3;
    int node = blockIdx.x * 32 + nl;
    bool valid = node < nd;

    if (D == 32) {
        for (int i = tid; i < 16 * 32; i += 256) {
            int k2 = i >> 5, dim = i & 31;
            sWb[0 * 512 + i] = bfpack(r0.W[(2 * k2) * 32 + dim], r0.W[(2 * k2 + 1) * 32 + dim]);
            if (NREL > 1) sWb[1 * 512 + i] = bfpack(r1.W[(2 * k2) * 32 + dim], r1.W[(2 * k2 + 1) * 32 + dim]);
            if (NREL > 2) sWb[2 * 512 + i] = bfpack(r2.W[(2 * k2) * 32 + dim], r2.W[(2 * k2 + 1) * 32 + dim]);
        }
    } else {
        for (int i = tid; i < 6 * 32; i += 256) {
            sW6[0 * 192 + i] = r0.W[i];
            if (NREL > 1) sW6[1 * 192 + i] = r1.W[i];
            if (NREL > 2) sW6[2 * 192 + i] = r2.W[i];
        }
    }
    for (int i = tid; i < D * 32; i += 256) {
        float wv = r0.Wroot[i];
        if (NREL > 1) wv += r1.Wroot[i];
        if (NREL > 2) wv += r2.Wroot[i];
        sWr[i] = wv;
    }

    if (D == 32) {
        uint2 xv = {0u, 0u};
        if (valid) xv = *reinterpret_cast<const uint2*>((const u32*)xdst + (size_t)node * 16 + l8 * 2);
        xP[nl * 16 + l8 * 2] = xv.x;
        xP[nl * 16 + l8 * 2 + 1] = xv.y;
    } else {
        float xv = (valid && l8 < 6) ? ((const float*)xdst)[(size_t)node * 6 + l8] : 0.f;
        xF[nl * 8 + l8] = xv;
    }

    do_gather<D, A0>(r0, node, nd, li, l8, nl, aggP + 0 * 32 * 16, aggF + 0 * 32 * 8);
    if (NREL > 1) do_gather<D, A1>(r1, node, nd, li, l8, nl, aggP + 1 * 32 * 16, aggF + 1 * 32 * 8);
    if (NREL > 2) do_gather<D, A2>(r2, node, nd, li, l8, nl, aggP + 2 * 32 * 16, aggF + 2 * 32 * 8);

    __syncthreads();

    int dim = tid & 31, grp = tid >> 5;
    #pragma unroll
    for (int it = 0; it < 4; ++it) {
        int n2 = grp + it * 8;
        int gnode = blockIdx.x * 32 + n2;
        if (gnode < nd) {
            float mm = r0.b[dim];
            if (NREL > 1) mm += r1.b[dim];
            if (NREL > 2) mm += r2.b[dim];
            if (D == 32) {
                #pragma unroll
                for (int r = 0; r < NREL; ++r) {
                    const u32* ar = aggP + r * 32 * 16 + n2 * 16;
                    const u32* wr = sWb + r * 512;
                    #pragma unroll
                    for (int k2 = 0; k2 < 16; ++k2) {
                        u32 a = ar[k2];
                        u32 w = wr[k2 * 32 + dim];
                        mm = fmaf(bflo(a), bflo(w), mm);
                        mm = fmaf(bfhi(a), bfhi(w), mm);
                    }
                }
                const u32* xr = xP + n2 * 16;
                #pragma unroll
                for (int k2 = 0; k2 < 16; ++k2) {
                    u32 u = xr[k2];
                    mm = fmaf(bflo(u), sWr[(2 * k2) * 32 + dim], mm);
                    mm = fmaf(bfhi(u), sWr[(2 * k2 + 1) * 32 + dim], mm);
                }
                if (RES) {
                    u32 u = xr[dim >> 1];
                    mm += (dim & 1) ? bfhi(u) : bflo(u);
                }
            } else {
                #pragma unroll
                for (int r = 0; r < NREL; ++r)
                    #pragma unroll
                    for (int k = 0; k < 6; ++k)
                        mm = fmaf(aggF[r * 32 * 8 + n2 * 8 + k], sW6[r * 192 + k * 32 + dim], mm);
                #pragma unroll
                for (int k = 0; k < 6; ++k)
                    mm = fmaf(xF[n2 * 8 + k], sWr[k * 32 + dim], mm);
            }
            if (RELU) mm = fmaxf(mm, 0.f);
            if (OUTBF) ((u16*)outp)[(size_t)gnode * 32 + dim] = bf1(mm);
            else       ((float*)outp)[(size_t)gnode * 32 + dim] = mm;
        }
    }
}

// ---------------- host ----------------

static inline char* alignp(char* p, size_t a) {
    return (char*)(((uintptr_t)p + a - 1) & ~(a - 1));
}

extern "C" void kernel_launch(void* const* d_in, const int* in_sizes, int n_in,
                              void* d_out, int out_size, void* d_ws, size_t ws_size,
                              hipStream_t stream)
{
    const float* x_stroke = (const float*)d_in[0];
    const float* x_brep   = (const float*)d_in[1];
    const int* ei0 = (const int*)d_in[2];
    const int* ei1 = (const int*)d_in[3];
    const int* ei2 = (const int*)d_in[4];
    const int* ei3 = (const int*)d_in[5];
    const int* ei4 = (const int*)d_in[6];
    const float* W0_rel  = (const float*)d_in[7];
    const float* b0_rel  = (const float*)d_in[8];
    const float* W0_root = (const float*)d_in[9];
    const float* Wb_rel  = (const float*)d_in[10];
    const float* bb_rel  = (const float*)d_in[11];
    const float* Wb_root = (const float*)d_in[12];
    float* out = (float*)d_out;

    // ---- workspace ----
    char* A = alignp((char*)d_ws, 256);
    int* ebkt = (int*)A;                                 // 5*EE ints (dead after csr_kernel)
    u32* xs0 = (u32*)A;                                  // overlay: bf16 feats (16 u32/node)
    u32* xb0 = xs0 + (size_t)NS * 16;
    char* Aend = (char*)(ebkt + (size_t)5 * EE);
    u32* xs1 = (u32*)alignp(Aend, 256);
    u32* xb1 = xs1 + (size_t)NS * 16;
    int* edges_csr = (int*)alignp((char*)(xb1 + (size_t)NB * 16), 256);   // 5*EE
    int* rs_all = (int*)alignp((char*)(edges_csr + (size_t)5 * EE), 256); // 5*(NS+1)
    int* bcnt  = (int*)alignp((char*)(rs_all + 5 * (NS + 1)), 256);
    int* bbase = (int*)alignp((char*)(bcnt + 5 * NBK_S), 256);
    int* gcur  = (int*)alignp((char*)(bbase + 5 * NBK_S), 256);

    // ---- build ----
    hipMemsetAsync(bcnt, 0, 5 * NBK_S * sizeof(int), stream);
    hist_kernel<<<dim3(NCH, 5), 256, 0, stream>>>(ei0, ei1, ei2, ei3, ei4, bcnt);
    bscan_kernel<<<5, 512, 0, stream>>>(bcnt, bbase, gcur);
    sort_kernel<<<dim3(NSC, 5), 256, 0, stream>>>(ei0, ei1, ei2, ei3, ei4, ebkt, gcur);
    csr_kernel<<<dim3(NBK_S, 5), 256, 0, stream>>>(ebkt, bcnt, bbase, edges_csr, rs_all);

    // ---- weights ----
    auto relW = [&](int l, int r) -> const float* {
        return l == 0 ? W0_rel + r * 6 * 32 : Wb_rel + ((l - 1) * 5 + r) * 32 * 32;
    };
    auto relB = [&](int l, int r) -> const float* {
        return l == 0 ? b0_rel + r * 32 : bb_rel + ((l - 1) * 5 + r) * 32;
    };
    auto relWr = [&](int l, int r) -> const float* {
        return l == 0 ? W0_root + r * 6 * 32 : Wb_root + ((l - 1) * 5 + r) * 32 * 32;
    };
    auto FR = [&](int l, int r, const void* xsrc) -> FRel {
        FRel R;
        R.rs = rs_all + r * (NS + 1);
        R.srcs = edges_csr + (size_t)r * EE;
        R.xsrc = xsrc;
        R.W = relW(l, r); R.b = relB(l, r); R.Wroot = relWr(l, r);
        return R;
    };

    const int GS = (NS + 31) / 32;   // 3125
    const int GB = (NB + 31) / 32;   // 1563

    // layer 0 (D=6 f32 inputs, no residual) -> bf16 xs0/xb0
    fused_kernel<6, 3, false, false, true, 1, 0, 2><<<GS, 256, 0, stream>>>(
        FR(0, 0, x_stroke), FR(0, 1, x_stroke), FR(0, 4, x_stroke), x_stroke, xs0, NS);
    fused_kernel<6, 2, false, false, true, 1, 2, 0><<<GB, 256, 0, stream>>>(
        FR(0, 2, x_stroke), FR(0, 3, x_brep), FR(0, 2, x_stroke), x_brep, xb0, NB);

    // layers 1..3 (D=32 bf16, residual, ping-pong); layer 4 relu -> f32 d_out
    const u32* cs = xs0; const u32* cb = xb0;
    for (int l = 1; l <= 3; ++l) {
        u32* os = (l & 1) ? xs1 : xs0;
        u32* ob = (l & 1) ? xb1 : xb0;
        fused_kernel<32, 3, true, false, true, 1, 0, 2><<<GS, 256, 0, stream>>>(
            FR(l, 0, cs), FR(l, 1, cs), FR(l, 4, cs), cs, os, NS);
        fused_kernel<32, 2, true, false, true, 1, 2, 0><<<GB, 256, 0, stream>>>(
            FR(l, 2, cs), FR(l, 3, cb), FR(l, 2, cs), cb, ob, NB);
        cs = os; cb = ob;
    }
    fused_kernel<32, 3, true, true, false, 1, 0, 2><<<GS, 256, 0, stream>>>(
        FR(4, 0, cs), FR(4, 1, cs), FR(4, 4, cs), cs, out, NS);
    fused_kernel<32, 2, true, true, false, 1, 2, 0><<<GB, 256, 0, stream>>>(
        FR(4, 2, cs), FR(4, 3, cb), FR(4, 2, cs), cb, out + (size_t)NS * 32, NB);

    (void)in_sizes; (void)n_in; (void)out_size; (void)ws_size;
}